// Round 1
// baseline (5164.599 us; speedup 1.0000x reference)
//
#include <hip/hip_runtime.h>

#define NTOK 16384
#define NDIM 512

// ---------------------------------------------------------------------------
// GEMM: C = op(A@B)  64x64 tile, BK=16, 256 thr, 4x4 micro
// EPI 0: C = AB   1: C = relu(AB+bias)   2: C = C + AB + bias (in-place resid)
// ---------------------------------------------------------------------------
template<int EPI>
__global__ __launch_bounds__(256) void gemm_f32(
    const float* __restrict__ A, const float* __restrict__ B,
    float* __restrict__ C, const float* __restrict__ bias,
    int M, int N, int K)
{
  __shared__ float As[16][64];
  __shared__ float Bs[16][64];
  const int tid = threadIdx.x;
  const int row0 = blockIdx.y * 64, col0 = blockIdx.x * 64;
  const int ty = tid >> 4, tx = tid & 15;
  const int ar = tid >> 2, ac = (tid & 3) << 2;
  const int bk = tid >> 4, bj = (tid & 15) << 2;
  float acc[4][4] = {};
  for (int k0 = 0; k0 < K; k0 += 16) {
    float4 a = make_float4(0.f, 0.f, 0.f, 0.f);
    if (row0 + ar < M) a = *(const float4*)(A + (size_t)(row0 + ar) * K + k0 + ac);
    As[ac + 0][ar] = a.x; As[ac + 1][ar] = a.y; As[ac + 2][ar] = a.z; As[ac + 3][ar] = a.w;
    *(float4*)&Bs[bk][bj] = *(const float4*)(B + (size_t)(k0 + bk) * N + col0 + bj);
    __syncthreads();
#pragma unroll
    for (int kk = 0; kk < 16; kk++) {
      float4 av = *(float4*)&As[kk][ty << 2];
      float4 bv = *(float4*)&Bs[kk][tx << 2];
      float a4[4] = {av.x, av.y, av.z, av.w};
      float b4[4] = {bv.x, bv.y, bv.z, bv.w};
#pragma unroll
      for (int ii = 0; ii < 4; ii++)
#pragma unroll
        for (int jj = 0; jj < 4; jj++) acc[ii][jj] += a4[ii] * b4[jj];
    }
    __syncthreads();
  }
#pragma unroll
  for (int ii = 0; ii < 4; ii++) {
    int gr = row0 + (ty << 2) + ii;
    if (gr < M) {
#pragma unroll
      for (int jj = 0; jj < 4; jj++) {
        int gc = col0 + (tx << 2) + jj;
        float v = acc[ii][jj];
        if (EPI == 1) { v += bias[gc]; v = fmaxf(v, 0.f); }
        if (EPI == 2) { v += bias[gc] + C[(size_t)gr * N + gc]; }
        C[(size_t)gr * N + gc] = v;
      }
    }
  }
}

// ---------------------------------------------------------------------------
// Batched (z=8 heads) GEMM for pinv: C = alpha*(A@B) + beta*I
// ---------------------------------------------------------------------------
__global__ __launch_bounds__(256) void bmm_f32(
    const float* __restrict__ A, const float* __restrict__ B, float* __restrict__ C,
    int M, int N, int K, float alpha, float beta)
{
  const int h = blockIdx.z;
  A += (size_t)h * M * K; B += (size_t)h * K * N; C += (size_t)h * M * N;
  __shared__ float As[16][64];
  __shared__ float Bs[16][64];
  const int tid = threadIdx.x;
  const int row0 = blockIdx.y * 64, col0 = blockIdx.x * 64;
  const int ty = tid >> 4, tx = tid & 15;
  const int ar = tid >> 2, ac = (tid & 3) << 2;
  const int bk = tid >> 4, bj = (tid & 15) << 2;
  float acc[4][4] = {};
  for (int k0 = 0; k0 < K; k0 += 16) {
    float4 a = *(const float4*)(A + (size_t)(row0 + ar) * K + k0 + ac);
    As[ac + 0][ar] = a.x; As[ac + 1][ar] = a.y; As[ac + 2][ar] = a.z; As[ac + 3][ar] = a.w;
    *(float4*)&Bs[bk][bj] = *(const float4*)(B + (size_t)(k0 + bk) * N + col0 + bj);
    __syncthreads();
#pragma unroll
    for (int kk = 0; kk < 16; kk++) {
      float4 av = *(float4*)&As[kk][ty << 2];
      float4 bv = *(float4*)&Bs[kk][tx << 2];
      float a4[4] = {av.x, av.y, av.z, av.w};
      float b4[4] = {bv.x, bv.y, bv.z, bv.w};
#pragma unroll
      for (int ii = 0; ii < 4; ii++)
#pragma unroll
        for (int jj = 0; jj < 4; jj++) acc[ii][jj] += a4[ii] * b4[jj];
    }
    __syncthreads();
  }
#pragma unroll
  for (int ii = 0; ii < 4; ii++) {
    int gr = row0 + (ty << 2) + ii;
#pragma unroll
    for (int jj = 0; jj < 4; jj++) {
      int gc = col0 + (tx << 2) + jj;
      float v = alpha * acc[ii][jj];
      if (gr == gc) v += beta;
      C[(size_t)gr * N + gc] = v;
    }
  }
}

// out = c*I - in   (8 x 256 x 256)
__global__ void eyesub(const float* __restrict__ in, float* __restrict__ out, float c) {
  int idx = blockIdx.x * 256 + threadIdx.x;
  int i = (idx >> 8) & 255, j = idx & 255;
  out[idx] = ((i == j) ? c : 0.f) - in[idx];
}

__global__ void cls_copy(const float* __restrict__ cls, float* __restrict__ h) {
  int t = threadIdx.x;
  if (t < 512) h[t] = cls[t];
}

// per-row layernorm over 512
__global__ __launch_bounds__(256) void layernorm_rows(
    const float* __restrict__ x, float* __restrict__ y,
    const float* __restrict__ w, const float* __restrict__ b)
{
  const int row = blockIdx.x, tid = threadIdx.x;
  const float* xr = x + (size_t)row * NDIM;
  float2 v = ((const float2*)xr)[tid];
  float sum = v.x + v.y, sq = v.x * v.x + v.y * v.y;
#pragma unroll
  for (int off = 32; off; off >>= 1) { sum += __shfl_xor(sum, off); sq += __shfl_xor(sq, off); }
  __shared__ float r1[4], r2[4];
  if ((tid & 63) == 0) { r1[tid >> 6] = sum; r2[tid >> 6] = sq; }
  __syncthreads();
  sum = r1[0] + r1[1] + r1[2] + r1[3];
  sq  = r2[0] + r2[1] + r2[2] + r2[3];
  float mu = sum * (1.f / 512.f);
  float var = sq * (1.f / 512.f) - mu * mu;
  float rs = rsqrtf(var + 1e-5f);
  float* yr = y + (size_t)row * NDIM;
  yr[2 * tid]     = (v.x - mu) * rs * w[2 * tid]     + b[2 * tid];
  yr[2 * tid + 1] = (v.y - mu) * rs * w[2 * tid + 1] + b[2 * tid + 1];
}

// landmark pooling (q scaled by dh^-0.5 = 1/8)
__global__ void pool_lm(const float* __restrict__ qkv,
                        float* __restrict__ q_l, float* __restrict__ k_l)
{
  int idx = blockIdx.x * 256 + threadIdx.x;          // (h,j,d) 8*256*64
  int d = idx & 63, j = (idx >> 6) & 255, h = idx >> 14;
  const float* bq = qkv + (size_t)(j << 6) * 1536 + (h << 6) + d;
  float sq = 0.f, sk = 0.f;
  for (int u = 0; u < 64; u++) { sq += bq[(size_t)u * 1536]; sk += bq[(size_t)u * 1536 + 512]; }
  q_l[idx] = sq * (1.f / 64.f) * 0.125f;
  k_l[idx] = sk * (1.f / 64.f);
}

// kT[h*64+d][i] = qkv[i][512 + h*64+d]
__global__ __launch_bounds__(256) void transpose_k(const float* __restrict__ qkv,
                                                   float* __restrict__ kT)
{
  __shared__ float tile[32][33];
  int i0 = blockIdx.x * 32, c0 = blockIdx.y * 32;
  int tx = threadIdx.x & 31, ty = threadIdx.x >> 5;
  for (int yy = ty; yy < 32; yy += 8)
    tile[yy][tx] = qkv[(size_t)(i0 + yy) * 1536 + 512 + c0 + tx];
  __syncthreads();
  for (int yy = ty; yy < 32; yy += 8)
    kT[(size_t)(c0 + yy) * NTOK + i0 + tx] = tile[tx][yy];
}

// attn2 = softmax(q_l @ k_l^T) rows
__global__ __launch_bounds__(256) void attn2_softmax(
    const float* __restrict__ q_l, const float* __restrict__ k_l, float* __restrict__ x2)
{
  int row = blockIdx.x, h = blockIdx.y, j = threadIdx.x;
  __shared__ float qrow[64];
  __shared__ float red[4];
  if (j < 64) qrow[j] = q_l[(size_t)(h * 256 + row) * 64 + j];
  __syncthreads();
  const float* kr = k_l + (size_t)(h * 256 + j) * 64;
  float s = 0.f;
#pragma unroll 8
  for (int d = 0; d < 64; d++) s += qrow[d] * kr[d];
  float m = s;
#pragma unroll
  for (int off = 32; off; off >>= 1) m = fmaxf(m, __shfl_xor(m, off));
  if ((j & 63) == 0) red[j >> 6] = m;
  __syncthreads();
  m = fmaxf(fmaxf(red[0], red[1]), fmaxf(red[2], red[3]));
  __syncthreads();
  float e = __expf(s - m), l = e;
#pragma unroll
  for (int off = 32; off; off >>= 1) l += __shfl_xor(l, off);
  if ((j & 63) == 0) red[j >> 6] = l;
  __syncthreads();
  l = red[0] + red[1] + red[2] + red[3];
  x2[((size_t)(h * 256 + row) << 8) + j] = e / l;
}

// global max row-sum / col-sum of attn2 (positive) via uint-bit atomicMax
__global__ __launch_bounds__(256) void colrow_max(const float* __restrict__ x2,
                                                  float* __restrict__ scal)
{
  int t = threadIdx.x, r = blockIdx.x, h = blockIdx.y;
  float rv = x2[((size_t)(h * 256 + r) << 8) + t];
  float cv = x2[((size_t)(h * 256 + t) << 8) + r];
#pragma unroll
  for (int off = 32; off; off >>= 1) { rv += __shfl_xor(rv, off); cv += __shfl_xor(cv, off); }
  __shared__ float rr[4], cc[4];
  if ((t & 63) == 0) { rr[t >> 6] = rv; cc[t >> 6] = cv; }
  __syncthreads();
  if (t == 0) {
    float rs = rr[0] + rr[1] + rr[2] + rr[3];
    float cs = cc[0] + cc[1] + cc[2] + cc[3];
    atomicMax((unsigned int*)&scal[0], __float_as_uint(rs));
    atomicMax((unsigned int*)&scal[1], __float_as_uint(cs));
  }
}

__global__ void zinit(const float* __restrict__ x2, float* __restrict__ z,
                      const float* __restrict__ scal)
{
  int idx = blockIdx.x * 256 + threadIdx.x;
  int h = idx >> 16, i = (idx >> 8) & 255, j = idx & 255;
  float denom = scal[0] * scal[1];
  z[idx] = x2[((size_t)(h * 256 + j) << 8) + i] / denom;
}

// attn3 softmax stats (m,l) partials: grid (8 heads, 8 rowchunks, 4 keychunks)
__global__ __launch_bounds__(256) void flash_ml(
    const float* __restrict__ q_l, const float* __restrict__ kT, float* __restrict__ mlp)
{
  const int h = blockIdx.x, rc = blockIdx.y, kc = blockIdx.z, tid = threadIdx.x;
  __shared__ float ql[32][64];
  __shared__ float redm[32][4], redl[32][4];
  const float* qsrc = q_l + ((size_t)(h * 256 + rc * 32) << 6);
  for (int e = tid; e < 2048; e += 256) (&ql[0][0])[e] = qsrc[e];
  __syncthreads();
  float m[32], l[32];
#pragma unroll
  for (int r = 0; r < 32; r++) { m[r] = -1e30f; l[r] = 0.f; }
  const float* kp0 = kT + ((size_t)h << 20);
  for (int step = 0; step < 16; step++) {
    int i = (kc << 12) + (step << 8) + tid;
    float s[32];
#pragma unroll
    for (int r = 0; r < 32; r++) s[r] = 0.f;
#pragma unroll 4
    for (int dd = 0; dd < 64; dd++) {
      float kd = kp0[((size_t)dd << 14) + i];
#pragma unroll
      for (int r = 0; r < 32; r++) s[r] += ql[r][dd] * kd;
    }
#pragma unroll
    for (int r = 0; r < 32; r++) {
      float mn = fmaxf(m[r], s[r]);
      l[r] = l[r] * __expf(m[r] - mn) + __expf(s[r] - mn);
      m[r] = mn;
    }
  }
#pragma unroll 1
  for (int r = 0; r < 32; r++) {
    float mm = m[r], ll = l[r];
#pragma unroll
    for (int off = 32; off; off >>= 1) {
      float om = __shfl_xor(mm, off), ol = __shfl_xor(ll, off);
      float mn = fmaxf(mm, om);
      ll = ll * __expf(mm - mn) + ol * __expf(om - mn);
      mm = mn;
    }
    if ((tid & 63) == 0) { redm[r][tid >> 6] = mm; redl[r][tid >> 6] = ll; }
  }
  __syncthreads();
  if (tid < 32) {
    float mm = -1e30f, ll = 0.f;
#pragma unroll
    for (int w = 0; w < 4; w++) {
      float om = redm[tid][w], ol = redl[tid][w];
      float mn = fmaxf(mm, om);
      ll = ll * __expf(mm - mn) + ol * __expf(om - mn);
      mm = mn;
    }
    int o = ((h * 4 + kc) * 256 + rc * 32 + tid) * 2;
    mlp[o] = mm; mlp[o + 1] = ll;
  }
}

__global__ void ml_merge(const float* __restrict__ mlp,
                         float* __restrict__ mfin, float* __restrict__ lfin)
{
  int h = blockIdx.x, r = threadIdx.x;
  float m = -1e30f, l = 0.f;
  for (int kc = 0; kc < 4; kc++) {
    int o = ((h * 4 + kc) * 256 + r) * 2;
    float m2 = mlp[o], l2 = mlp[o + 1];
    float mn = fmaxf(m, m2);
    l = l * __expf(m - mn) + l2 * __expf(m2 - mn);
    m = mn;
  }
  mfin[h * 256 + r] = m;
  lfin[h * 256 + r] = l;
}

// kv += P_chunk @ V_chunk  (attn3 @ v), grid (8, 8, 4)
__global__ __launch_bounds__(256) void flash_kv(
    const float* __restrict__ q_l, const float* __restrict__ kT,
    const float* __restrict__ qkv, const float* __restrict__ mfin,
    const float* __restrict__ lfin, float* __restrict__ kv)
{
  const int h = blockIdx.x, rc = blockIdx.y, kc = blockIdx.z, tid = threadIdx.x;
  const int d = tid & 63, grp = tid >> 6;
  __shared__ float ql[32][64];
  __shared__ float pt[64][33];
  __shared__ float mrow[32], lrow[32];
  const float* qsrc = q_l + ((size_t)(h * 256 + rc * 32) << 6);
  for (int e = tid; e < 2048; e += 256) (&ql[0][0])[e] = qsrc[e];
  if (tid < 32) {
    mrow[tid] = mfin[h * 256 + rc * 32 + tid];
    lrow[tid] = 1.f / lfin[h * 256 + rc * 32 + tid];
  }
  __syncthreads();
  float acc[8];
#pragma unroll
  for (int j = 0; j < 8; j++) acc[j] = 0.f;
  const float* kp0 = kT + ((size_t)h << 20);
  for (int t0 = 0; t0 < 4096; t0 += 64) {
    int i = (kc << 12) + t0 + d;   // d doubles as kk for score phase
    float s[8];
#pragma unroll
    for (int j = 0; j < 8; j++) s[j] = 0.f;
#pragma unroll 4
    for (int dd = 0; dd < 64; dd++) {
      float kd = kp0[((size_t)dd << 14) + i];
#pragma unroll
      for (int j = 0; j < 8; j++) s[j] += ql[(grp << 3) + j][dd] * kd;
    }
    __syncthreads();
#pragma unroll
    for (int j = 0; j < 8; j++) {
      int r = (grp << 3) + j;
      pt[d][r] = __expf(s[j] - mrow[r]) * lrow[r];
    }
    __syncthreads();
    const float* vp = qkv + (size_t)((kc << 12) + t0) * 1536 + 1024 + (h << 6) + d;
#pragma unroll 4
    for (int k2 = 0; k2 < 64; k2++) {
      float vv = vp[(size_t)k2 * 1536];
#pragma unroll
      for (int j = 0; j < 8; j++) acc[j] += pt[k2][(grp << 3) + j] * vv;
    }
  }
#pragma unroll
  for (int j = 0; j < 8; j++) {
    int row = rc * 32 + (grp << 3) + j;
    atomicAdd(&kv[((size_t)(h * 256 + row) << 6) + d], acc[j]);
  }
}

// fused: softmax(q@k_l^T) @ B + depthwise-conv(v) -> attn_out[i][h*64+d]
// grid (512 qchunks of 32, 8 heads)
__global__ __launch_bounds__(256) void attn1_out(
    const float* __restrict__ qkv, const float* __restrict__ k_l,
    const float* __restrict__ Bm, const float* __restrict__ res_k,
    float* __restrict__ attn_out)
{
  const int qc = blockIdx.x, h = blockIdx.y, tid = threadIdx.x;
  const int q0 = qc * 32;
  __shared__ float qt[32][64];
  __shared__ float st[32][257];
  __shared__ float rk[33];
  __shared__ float mrow[32], srow[32];
  __shared__ float red[32][8];
  for (int e = tid; e < 2048; e += 256) {
    int r = e >> 6, dd = e & 63;
    qt[r][dd] = qkv[(size_t)(q0 + r) * 1536 + (h << 6) + dd] * 0.125f;
  }
  if (tid < 33) rk[tid] = res_k[h * 33 + tid];
  __syncthreads();
  // phase 1: scores, thread = landmark j
  {
    float kreg[64];
    const float4* kr4 = (const float4*)(k_l + ((size_t)(h * 256 + tid) << 6));
#pragma unroll
    for (int u = 0; u < 16; u++) {
      float4 kv4 = kr4[u];
      kreg[4 * u] = kv4.x; kreg[4 * u + 1] = kv4.y; kreg[4 * u + 2] = kv4.z; kreg[4 * u + 3] = kv4.w;
    }
#pragma unroll 1
    for (int r = 0; r < 32; r++) {
      float s = 0.f;
#pragma unroll
      for (int dd = 0; dd < 64; dd++) s += qt[r][dd] * kreg[dd];
      st[r][tid] = s;
    }
  }
  __syncthreads();
  // phase 2: row max / sum (r = tid&31, seg = tid>>5 covers j in [seg*32, seg*32+32))
  {
    int r = tid & 31, seg = tid >> 5;
    float mx = -1e30f;
    for (int j = seg * 32; j < seg * 32 + 32; j++) mx = fmaxf(mx, st[r][j]);
    red[r][seg] = mx;
  }
  __syncthreads();
  if (tid < 32) {
    float mx = -1e30f;
#pragma unroll
    for (int s2 = 0; s2 < 8; s2++) mx = fmaxf(mx, red[tid][s2]);
    mrow[tid] = mx;
  }
  __syncthreads();
  {
    int r = tid & 31, seg = tid >> 5;
    float sm = 0.f, mx = mrow[r];
    for (int j = seg * 32; j < seg * 32 + 32; j++) {
      float e = __expf(st[r][j] - mx);
      st[r][j] = e;
      sm += e;
    }
    red[r][seg] = sm;
  }
  __syncthreads();
  if (tid < 32) {
    float sm = 0.f;
#pragma unroll
    for (int s2 = 0; s2 < 8; s2++) sm += red[tid][s2];
    srow[tid] = 1.f / sm;
  }
  __syncthreads();
  // phase 3: P @ B ; thread (d = tid&63, grp = tid>>6) owns rows grp*8..+8
  const int d = tid & 63, grp = tid >> 6;
  float acc[8];
#pragma unroll
  for (int j = 0; j < 8; j++) acc[j] = 0.f;
  const float* bp = Bm + ((size_t)h << 14) + d;   // B[h][j][d], stride 64
#pragma unroll 4
  for (int j = 0; j < 256; j++) {
    float bv = bp[(size_t)j << 6];
#pragma unroll
    for (int r8 = 0; r8 < 8; r8++) acc[r8] += st[(grp << 3) + r8][j] * bv;
  }
  // epilogue: normalize + depthwise conv residual + store
#pragma unroll 1
  for (int r8 = 0; r8 < 8; r8++) {
    int q = (grp << 3) + r8;
    int i = q0 + q;
    float v = acc[r8] * srow[q];
    float cv = 0.f;
#pragma unroll
    for (int u = 0; u < 33; u++) {
      int ii = i + u - 16;
      if (ii >= 0 && ii < NTOK)
        cv += rk[u] * qkv[(size_t)ii * 1536 + 1024 + (h << 6) + d];
    }
    attn_out[((size_t)i << 9) + (h << 6) + d] = v + cv;
  }
}

// final: layernorm row0 -> 4 logits -> sigmoid + cumprod
__global__ __launch_bounds__(256) void final_head(
    const float* __restrict__ hrow, const float* __restrict__ nw, const float* __restrict__ nb,
    const float* __restrict__ cw, const float* __restrict__ cb, float* __restrict__ out)
{
  const int tid = threadIdx.x;
  __shared__ float ln0[512];
  __shared__ float r1[4], r2[4];
  __shared__ float lg[4][4];
  float2 v = ((const float2*)hrow)[tid];
  float sum = v.x + v.y, sq = v.x * v.x + v.y * v.y;
#pragma unroll
  for (int off = 32; off; off >>= 1) { sum += __shfl_xor(sum, off); sq += __shfl_xor(sq, off); }
  if ((tid & 63) == 0) { r1[tid >> 6] = sum; r2[tid >> 6] = sq; }
  __syncthreads();
  sum = r1[0] + r1[1] + r1[2] + r1[3];
  sq  = r2[0] + r2[1] + r2[2] + r2[3];
  float mu = sum * (1.f / 512.f);
  float var = sq * (1.f / 512.f) - mu * mu;
  float rs = rsqrtf(var + 1e-5f);
  ln0[2 * tid]     = (v.x - mu) * rs * nw[2 * tid]     + nb[2 * tid];
  ln0[2 * tid + 1] = (v.y - mu) * rs * nw[2 * tid + 1] + nb[2 * tid + 1];
  __syncthreads();
  float p[4] = {0.f, 0.f, 0.f, 0.f};
  for (int k = tid; k < 512; k += 256) {
    float lv = ln0[k];
#pragma unroll
    for (int c = 0; c < 4; c++) p[c] += lv * cw[k * 4 + c];
  }
#pragma unroll
  for (int off = 32; off; off >>= 1)
#pragma unroll
    for (int c = 0; c < 4; c++) p[c] += __shfl_xor(p[c], off);
  if ((tid & 63) == 0) {
    int w = tid >> 6;
#pragma unroll
    for (int c = 0; c < 4; c++) lg[w][c] = p[c];
  }
  __syncthreads();
  if (tid == 0) {
    float cum = 1.f;
    for (int c = 0; c < 4; c++) {
      float logit = lg[0][c] + lg[1][c] + lg[2][c] + lg[3][c] + cb[c];
      float hz = 1.f / (1.f + __expf(-logit));
      out[c] = hz;
      cum *= (1.f - hz);
      out[4 + c] = cum;
    }
  }
}

// ---------------------------------------------------------------------------
extern "C" void kernel_launch(void* const* d_in, const int* in_sizes, int n_in,
                              void* d_out, int out_size, void* d_ws, size_t ws_size,
                              hipStream_t stream)
{
  (void)in_sizes; (void)n_in; (void)out_size; (void)ws_size;
  const float* x    = (const float*)d_in[0];
  const float* fc_w = (const float*)d_in[1];
  const float* fc_b = (const float*)d_in[2];
  const float* cls  = (const float*)d_in[3];
  const float* nw[2]   = {(const float*)d_in[4],  (const float*)d_in[10]};
  const float* nb[2]   = {(const float*)d_in[5],  (const float*)d_in[11]};
  const float* qkvw[2] = {(const float*)d_in[6],  (const float*)d_in[12]};
  const float* outw[2] = {(const float*)d_in[7],  (const float*)d_in[13]};
  const float* outb[2] = {(const float*)d_in[8],  (const float*)d_in[14]};
  const float* resk[2] = {(const float*)d_in[9],  (const float*)d_in[15]};
  const float* fnw = (const float*)d_in[16];
  const float* fnb = (const float*)d_in[17];
  const float* cw  = (const float*)d_in[18];
  const float* cb  = (const float*)d_in[19];

  float* ws = (float*)d_ws;
  float* h    = ws; ws += (size_t)NTOK * NDIM;
  float* ln   = ws; ws += (size_t)NTOK * NDIM;     // reused as attn_out
  float* qkv  = ws; ws += (size_t)NTOK * 1536;
  float* kT   = ws; ws += (size_t)NDIM * NTOK;
  float* q_l  = ws; ws += 8 * 256 * 64;
  float* k_l  = ws; ws += 8 * 256 * 64;
  float* x2   = ws; ws += 8 * 256 * 256;
  float* z0   = ws; ws += 8 * 256 * 256;
  float* z1   = ws; ws += 8 * 256 * 256;
  float* tA   = ws; ws += 8 * 256 * 256;
  float* tB   = ws; ws += 8 * 256 * 256;
  float* tC   = ws; ws += 8 * 256 * 256;
  float* mlp  = ws; ws += 8 * 4 * 256 * 2;
  float* mfin = ws; ws += 8 * 256;
  float* lfin = ws; ws += 8 * 256;
  float* kv   = ws; ws += 8 * 256 * 64;
  float* Bm   = ws; ws += 8 * 256 * 64;
  float* scal = ws; ws += 64;

  // fc + relu into h rows 1..16383 ; cls token -> row 0
  gemm_f32<1><<<dim3(512 / 64, (16383 + 63) / 64), 256, 0, stream>>>(
      x, fc_w, h + 512, fc_b, 16383, 512, 1024);
  cls_copy<<<1, 512, 0, stream>>>(cls, h);

  for (int L = 0; L < 2; L++) {
    layernorm_rows<<<NTOK, 256, 0, stream>>>(h, ln, nw[L], nb[L]);
    gemm_f32<0><<<dim3(1536 / 64, NTOK / 64), 256, 0, stream>>>(
        ln, qkvw[L], qkv, nullptr, NTOK, 1536, 512);
    pool_lm<<<512, 256, 0, stream>>>(qkv, q_l, k_l);
    transpose_k<<<dim3(NTOK / 32, 512 / 32), 256, 0, stream>>>(qkv, kT);
    attn2_softmax<<<dim3(256, 8), 256, 0, stream>>>(q_l, k_l, x2);
    hipMemsetAsync(scal, 0, 2 * sizeof(float), stream);
    colrow_max<<<dim3(256, 8), 256, 0, stream>>>(x2, scal);
    zinit<<<2048, 256, 0, stream>>>(x2, z0, scal);
    float* zin = z0; float* zout = z1;
    for (int it = 0; it < 6; it++) {
      bmm_f32<<<dim3(4, 4, 8), 256, 0, stream>>>(x2, zin, tA, 256, 256, 256, 1.f, 0.f);
      eyesub<<<2048, 256, 0, stream>>>(tA, tB, 7.f);
      bmm_f32<<<dim3(4, 4, 8), 256, 0, stream>>>(tA, tB, tC, 256, 256, 256, -1.f, 15.f);
      bmm_f32<<<dim3(4, 4, 8), 256, 0, stream>>>(tA, tC, tB, 256, 256, 256, -1.f, 13.f);
      bmm_f32<<<dim3(4, 4, 8), 256, 0, stream>>>(zin, tB, zout, 256, 256, 256, 0.25f, 0.f);
      float* t = zin; zin = zout; zout = t;
    }
    flash_ml<<<dim3(8, 8, 4), 256, 0, stream>>>(q_l, kT, mlp);
    ml_merge<<<8, 256, 0, stream>>>(mlp, mfin, lfin);
    hipMemsetAsync(kv, 0, (size_t)8 * 256 * 64 * sizeof(float), stream);
    flash_kv<<<dim3(8, 8, 4), 256, 0, stream>>>(q_l, kT, qkv, mfin, lfin, kv);
    bmm_f32<<<dim3(1, 4, 8), 256, 0, stream>>>(zin, kv, Bm, 256, 64, 256, 1.f, 0.f);
    attn1_out<<<dim3(512, 8), 256, 0, stream>>>(qkv, k_l, Bm, resk[L], ln);
    gemm_f32<2><<<dim3(512 / 64, NTOK / 64), 256, 0, stream>>>(
        ln, outw[L], h, outb[L], NTOK, 512, 512);
  }
  final_head<<<1, 256, 0, stream>>>(h, fnw, fnb, cw, cb, (float*)d_out);
}

// Round 2
// 3127.204 us; speedup vs baseline: 1.6515x; 1.6515x over previous
//
#include <hip/hip_runtime.h>

#define NTOK 16384
#define NDIM 512

typedef __attribute__((ext_vector_type(8))) short short8;
typedef __attribute__((ext_vector_type(4))) float f32x4;

__device__ __forceinline__ unsigned short f2bf(float f) {
  unsigned u = __float_as_uint(f);
  u += 0x7fffu + ((u >> 16) & 1u);
  return (unsigned short)(u >> 16);
}

__device__ __forceinline__ void gload_lds16(const void* g, void* l) {
  __builtin_amdgcn_global_load_lds(
      (const __attribute__((address_space(1))) unsigned int*)(unsigned long long)(g),
      (__attribute__((address_space(3))) unsigned int*)(unsigned long long)(l), 16, 0, 0);
}

// ---------------------------------------------------------------------------
// bf16 MFMA GEMM: C(f32)[M][N] = epi(A(bf16)[M][K] @ Bt(bf16)[N][K]^T)
// 128x128 tile, BK=32, 256 thr (4 waves 2x2), wave does 64x64 via 4x4 mfma
// EPI 0: C=AB   1: C=relu(AB+bias)   2: C+=AB+bias
// ---------------------------------------------------------------------------
template<int EPI>
__global__ __launch_bounds__(256) void gemm_bf16(
    const unsigned short* __restrict__ A, const unsigned short* __restrict__ Bt,
    float* __restrict__ C, const float* __restrict__ bias,
    int M, int N, int K, int Mstore)
{
  __shared__ unsigned short As[128 * 32];
  __shared__ unsigned short Bs[128 * 32];
  const int tid = threadIdx.x;
  const int row0 = blockIdx.y * 128, col0 = blockIdx.x * 128;
  const int wave = tid >> 6, lane = tid & 63;
  const int wm = (wave >> 1) * 64, wn = (wave & 1) * 64;
  const int quad = lane >> 4, m16 = lane & 15;

  const int r0 = tid >> 2;
  const int c8 = (tid & 3) * 8;
  const unsigned short* Ag0 = A + (size_t)(row0 + r0) * K + c8;
  const unsigned short* Ag1 = A + (size_t)(row0 + r0 + 64) * K + c8;
  const unsigned short* Bg0 = Bt + (size_t)(col0 + r0) * K + c8;
  const unsigned short* Bg1 = Bt + (size_t)(col0 + r0 + 64) * K + c8;
  char* AsB = (char*)As;
  char* BsB = (char*)Bs;
  const int wb = wave * 1024;

  f32x4 acc[4][4] = {};
  for (int k0 = 0; k0 < K; k0 += 32) {
    gload_lds16(Ag0 + k0, AsB + wb);
    gload_lds16(Ag1 + k0, AsB + 4096 + wb);
    gload_lds16(Bg0 + k0, BsB + wb);
    gload_lds16(Bg1 + k0, BsB + 4096 + wb);
    __syncthreads();
    short8 af[4], bf[4];
#pragma unroll
    for (int i = 0; i < 4; i++) {
      af[i] = *(const short8*)&As[(wm + i * 16 + m16) * 32 + quad * 8];
      bf[i] = *(const short8*)&Bs[(wn + i * 16 + m16) * 32 + quad * 8];
    }
#pragma unroll
    for (int i = 0; i < 4; i++)
#pragma unroll
      for (int j = 0; j < 4; j++)
        acc[i][j] = __builtin_amdgcn_mfma_f32_16x16x32_bf16(af[i], bf[j], acc[i][j], 0, 0, 0);
    __syncthreads();
  }
#pragma unroll
  for (int i = 0; i < 4; i++) {
#pragma unroll
    for (int r = 0; r < 4; r++) {
      int gr = row0 + wm + i * 16 + quad * 4 + r;
      if (gr < Mstore) {
#pragma unroll
        for (int j = 0; j < 4; j++) {
          int gc = col0 + wn + j * 16 + m16;
          float v = acc[i][j][r];
          if (EPI == 1) { v += bias[gc]; v = fmaxf(v, 0.f); }
          if (EPI == 2) { v += bias[gc] + C[(size_t)gr * N + gc]; }
          C[(size_t)gr * N + gc] = v;
        }
      }
    }
  }
}

// cast fp32 -> bf16, pad (zero) past nvalid elements
__global__ void castpad_x(const float* __restrict__ x, unsigned short* __restrict__ xb,
                          size_t nvalid) {
  size_t i4 = ((size_t)blockIdx.x * 256 + threadIdx.x) * 4;
  float4 v = make_float4(0.f, 0.f, 0.f, 0.f);
  if (i4 < nvalid) v = *(const float4*)(x + i4);
  ushort4 o;
  o.x = f2bf(v.x); o.y = f2bf(v.y); o.z = f2bf(v.z); o.w = f2bf(v.w);
  *(ushort4*)(xb + i4) = o;
}

// in fp32 [R][C] -> out bf16 [C][R]
__global__ __launch_bounds__(256) void transpose_cast(
    const float* __restrict__ in, unsigned short* __restrict__ out, int R, int C)
{
  __shared__ float tile[32][33];
  int r0 = blockIdx.x * 32, c0 = blockIdx.y * 32;
  int tx = threadIdx.x & 31, ty = threadIdx.x >> 5;
  for (int yy = ty; yy < 32; yy += 8)
    tile[yy][tx] = in[(size_t)(r0 + yy) * C + c0 + tx];
  __syncthreads();
  for (int yy = ty; yy < 32; yy += 8)
    out[(size_t)(c0 + yy) * R + r0 + tx] = f2bf(tile[tx][yy]);
}

// ---------------------------------------------------------------------------
// Batched (z=8 heads) fp32 GEMM for pinv: C = alpha*(A@B) + beta*I
// ---------------------------------------------------------------------------
__global__ __launch_bounds__(256) void bmm_f32(
    const float* __restrict__ A, const float* __restrict__ B, float* __restrict__ C,
    int M, int N, int K, float alpha, float beta)
{
  const int h = blockIdx.z;
  A += (size_t)h * M * K; B += (size_t)h * K * N; C += (size_t)h * M * N;
  __shared__ float As[16][64];
  __shared__ float Bs[16][64];
  const int tid = threadIdx.x;
  const int row0 = blockIdx.y * 64, col0 = blockIdx.x * 64;
  const int ty = tid >> 4, tx = tid & 15;
  const int ar = tid >> 2, ac = (tid & 3) << 2;
  const int bk = tid >> 4, bj = (tid & 15) << 2;
  float acc[4][4] = {};
  for (int k0 = 0; k0 < K; k0 += 16) {
    float4 a = *(const float4*)(A + (size_t)(row0 + ar) * K + k0 + ac);
    As[ac + 0][ar] = a.x; As[ac + 1][ar] = a.y; As[ac + 2][ar] = a.z; As[ac + 3][ar] = a.w;
    *(float4*)&Bs[bk][bj] = *(const float4*)(B + (size_t)(k0 + bk) * N + col0 + bj);
    __syncthreads();
#pragma unroll
    for (int kk = 0; kk < 16; kk++) {
      float4 av = *(float4*)&As[kk][ty << 2];
      float4 bv = *(float4*)&Bs[kk][tx << 2];
      float a4[4] = {av.x, av.y, av.z, av.w};
      float b4[4] = {bv.x, bv.y, bv.z, bv.w};
#pragma unroll
      for (int ii = 0; ii < 4; ii++)
#pragma unroll
        for (int jj = 0; jj < 4; jj++) acc[ii][jj] += a4[ii] * b4[jj];
    }
    __syncthreads();
  }
#pragma unroll
  for (int ii = 0; ii < 4; ii++) {
    int gr = row0 + (ty << 2) + ii;
#pragma unroll
    for (int jj = 0; jj < 4; jj++) {
      int gc = col0 + (tx << 2) + jj;
      float v = alpha * acc[ii][jj];
      if (gr == gc) v += beta;
      C[(size_t)gr * N + gc] = v;
    }
  }
}

// out = c*I - in   (8 x 256 x 256)
__global__ void eyesub(const float* __restrict__ in, float* __restrict__ out, float c) {
  int idx = blockIdx.x * 256 + threadIdx.x;
  int i = (idx >> 8) & 255, j = idx & 255;
  out[idx] = ((i == j) ? c : 0.f) - in[idx];
}

__global__ void cls_copy(const float* __restrict__ cls, float* __restrict__ h) {
  int t = threadIdx.x;
  if (t < 512) h[t] = cls[t];
}

// per-row layernorm over 512, writes bf16
__global__ __launch_bounds__(256) void layernorm_rows(
    const float* __restrict__ x, unsigned short* __restrict__ y,
    const float* __restrict__ w, const float* __restrict__ b)
{
  const int row = blockIdx.x, tid = threadIdx.x;
  const float* xr = x + (size_t)row * NDIM;
  float2 v = ((const float2*)xr)[tid];
  float sum = v.x + v.y, sq = v.x * v.x + v.y * v.y;
#pragma unroll
  for (int off = 32; off; off >>= 1) { sum += __shfl_xor(sum, off); sq += __shfl_xor(sq, off); }
  __shared__ float r1[4], r2[4];
  if ((tid & 63) == 0) { r1[tid >> 6] = sum; r2[tid >> 6] = sq; }
  __syncthreads();
  sum = r1[0] + r1[1] + r1[2] + r1[3];
  sq  = r2[0] + r2[1] + r2[2] + r2[3];
  float mu = sum * (1.f / 512.f);
  float var = sq * (1.f / 512.f) - mu * mu;
  float rs = rsqrtf(var + 1e-5f);
  float a = (v.x - mu) * rs * w[2 * tid]     + b[2 * tid];
  float c = (v.y - mu) * rs * w[2 * tid + 1] + b[2 * tid + 1];
  ((unsigned*)(y + (size_t)row * NDIM))[tid] = (unsigned)f2bf(a) | ((unsigned)f2bf(c) << 16);
}

// landmark pooling (q scaled by dh^-0.5 = 1/8)
__global__ void pool_lm(const float* __restrict__ qkv,
                        float* __restrict__ q_l, float* __restrict__ k_l)
{
  int idx = blockIdx.x * 256 + threadIdx.x;          // (h,j,d) 8*256*64
  int d = idx & 63, j = (idx >> 6) & 255, h = idx >> 14;
  const float* bq = qkv + (size_t)(j << 6) * 1536 + (h << 6) + d;
  float sq = 0.f, sk = 0.f;
  for (int u = 0; u < 64; u++) { sq += bq[(size_t)u * 1536]; sk += bq[(size_t)u * 1536 + 512]; }
  q_l[idx] = sq * (1.f / 64.f) * 0.125f;
  k_l[idx] = sk * (1.f / 64.f);
}

// kT[h*64+d][i] = qkv[i][512 + h*64+d]
__global__ __launch_bounds__(256) void transpose_k(const float* __restrict__ qkv,
                                                   float* __restrict__ kT)
{
  __shared__ float tile[32][33];
  int i0 = blockIdx.x * 32, c0 = blockIdx.y * 32;
  int tx = threadIdx.x & 31, ty = threadIdx.x >> 5;
  for (int yy = ty; yy < 32; yy += 8)
    tile[yy][tx] = qkv[(size_t)(i0 + yy) * 1536 + 512 + c0 + tx];
  __syncthreads();
  for (int yy = ty; yy < 32; yy += 8)
    kT[(size_t)(c0 + yy) * NTOK + i0 + tx] = tile[tx][yy];
}

// attn2 = softmax(q_l @ k_l^T) rows
__global__ __launch_bounds__(256) void attn2_softmax(
    const float* __restrict__ q_l, const float* __restrict__ k_l, float* __restrict__ x2)
{
  int row = blockIdx.x, h = blockIdx.y, j = threadIdx.x;
  __shared__ float qrow[64];
  __shared__ float red[4];
  if (j < 64) qrow[j] = q_l[(size_t)(h * 256 + row) * 64 + j];
  __syncthreads();
  const float* kr = k_l + (size_t)(h * 256 + j) * 64;
  float s = 0.f;
#pragma unroll 8
  for (int d = 0; d < 64; d++) s += qrow[d] * kr[d];
  float m = s;
#pragma unroll
  for (int off = 32; off; off >>= 1) m = fmaxf(m, __shfl_xor(m, off));
  if ((j & 63) == 0) red[j >> 6] = m;
  __syncthreads();
  m = fmaxf(fmaxf(red[0], red[1]), fmaxf(red[2], red[3]));
  __syncthreads();
  float e = __expf(s - m), l = e;
#pragma unroll
  for (int off = 32; off; off >>= 1) l += __shfl_xor(l, off);
  if ((j & 63) == 0) red[j >> 6] = l;
  __syncthreads();
  l = red[0] + red[1] + red[2] + red[3];
  x2[((size_t)(h * 256 + row) << 8) + j] = e / l;
}

// global max row-sum / col-sum of attn2 (positive) via uint-bit atomicMax
__global__ __launch_bounds__(256) void colrow_max(const float* __restrict__ x2,
                                                  float* __restrict__ scal)
{
  int t = threadIdx.x, r = blockIdx.x, h = blockIdx.y;
  float rv = x2[((size_t)(h * 256 + r) << 8) + t];
  float cv = x2[((size_t)(h * 256 + t) << 8) + r];
#pragma unroll
  for (int off = 32; off; off >>= 1) { rv += __shfl_xor(rv, off); cv += __shfl_xor(cv, off); }
  __shared__ float rr[4], cc[4];
  if ((t & 63) == 0) { rr[t >> 6] = rv; cc[t >> 6] = cv; }
  __syncthreads();
  if (t == 0) {
    float rs = rr[0] + rr[1] + rr[2] + rr[3];
    float cs = cc[0] + cc[1] + cc[2] + cc[3];
    atomicMax((unsigned int*)&scal[0], __float_as_uint(rs));
    atomicMax((unsigned int*)&scal[1], __float_as_uint(cs));
  }
}

__global__ void zinit(const float* __restrict__ x2, float* __restrict__ z,
                      const float* __restrict__ scal)
{
  int idx = blockIdx.x * 256 + threadIdx.x;
  int h = idx >> 16, i = (idx >> 8) & 255, j = idx & 255;
  float denom = scal[0] * scal[1];
  z[idx] = x2[((size_t)(h * 256 + j) << 8) + i] / denom;
}

// attn3 softmax stats (m,l) partials: grid (8 heads, 8 rowchunks, 16 keychunks)
__global__ __launch_bounds__(256) void flash_ml(
    const float* __restrict__ q_l, const float* __restrict__ kT, float* __restrict__ mlp)
{
  const int h = blockIdx.x, rc = blockIdx.y, kc = blockIdx.z, tid = threadIdx.x;
  __shared__ float ql[32][64];
  __shared__ float redm[32][4], redl[32][4];
  const float* qsrc = q_l + ((size_t)(h * 256 + rc * 32) << 6);
  for (int e = tid; e < 2048; e += 256) (&ql[0][0])[e] = qsrc[e];
  __syncthreads();
  float m[32], l[32];
#pragma unroll
  for (int r = 0; r < 32; r++) { m[r] = -1e30f; l[r] = 0.f; }
  const float* kp0 = kT + ((size_t)h << 20);
  for (int step = 0; step < 4; step++) {
    int i = (kc << 10) + (step << 8) + tid;
    float s[32];
#pragma unroll
    for (int r = 0; r < 32; r++) s[r] = 0.f;
#pragma unroll 4
    for (int dd = 0; dd < 64; dd++) {
      float kd = kp0[((size_t)dd << 14) + i];
#pragma unroll
      for (int r = 0; r < 32; r++) s[r] += ql[r][dd] * kd;
    }
#pragma unroll
    for (int r = 0; r < 32; r++) {
      float mn = fmaxf(m[r], s[r]);
      l[r] = l[r] * __expf(m[r] - mn) + __expf(s[r] - mn);
      m[r] = mn;
    }
  }
#pragma unroll 1
  for (int r = 0; r < 32; r++) {
    float mm = m[r], ll = l[r];
#pragma unroll
    for (int off = 32; off; off >>= 1) {
      float om = __shfl_xor(mm, off), ol = __shfl_xor(ll, off);
      float mn = fmaxf(mm, om);
      ll = ll * __expf(mm - mn) + ol * __expf(om - mn);
      mm = mn;
    }
    if ((tid & 63) == 0) { redm[r][tid >> 6] = mm; redl[r][tid >> 6] = ll; }
  }
  __syncthreads();
  if (tid < 32) {
    float mm = -1e30f, ll = 0.f;
#pragma unroll
    for (int w = 0; w < 4; w++) {
      float om = redm[tid][w], ol = redl[tid][w];
      float mn = fmaxf(mm, om);
      ll = ll * __expf(mm - mn) + ol * __expf(om - mn);
      mm = mn;
    }
    int o = ((h * 16 + kc) * 256 + rc * 32 + tid) * 2;
    mlp[o] = mm; mlp[o + 1] = ll;
  }
}

__global__ void ml_merge(const float* __restrict__ mlp,
                         float* __restrict__ mfin, float* __restrict__ lfin)
{
  int h = blockIdx.x, r = threadIdx.x;
  float m = -1e30f, l = 0.f;
  for (int kc = 0; kc < 16; kc++) {
    int o = ((h * 16 + kc) * 256 + r) * 2;
    float m2 = mlp[o], l2 = mlp[o + 1];
    float mn = fmaxf(m, m2);
    l = l * __expf(m - mn) + l2 * __expf(m2 - mn);
    m = mn;
  }
  mfin[h * 256 + r] = m;
  lfin[h * 256 + r] = l;
}

// kv += P_chunk @ V_chunk  (attn3 @ v), grid (8, 8, 16)
__global__ __launch_bounds__(256) void flash_kv(
    const float* __restrict__ q_l, const float* __restrict__ kT,
    const float* __restrict__ qkv, const float* __restrict__ mfin,
    const float* __restrict__ lfin, float* __restrict__ kv)
{
  const int h = blockIdx.x, rc = blockIdx.y, kc = blockIdx.z, tid = threadIdx.x;
  const int d = tid & 63, grp = tid >> 6;
  __shared__ float ql[32][64];
  __shared__ float pt[64][33];
  __shared__ float mrow[32], lrow[32];
  const float* qsrc = q_l + ((size_t)(h * 256 + rc * 32) << 6);
  for (int e = tid; e < 2048; e += 256) (&ql[0][0])[e] = qsrc[e];
  if (tid < 32) {
    mrow[tid] = mfin[h * 256 + rc * 32 + tid];
    lrow[tid] = 1.f / lfin[h * 256 + rc * 32 + tid];
  }
  __syncthreads();
  float acc[8];
#pragma unroll
  for (int j = 0; j < 8; j++) acc[j] = 0.f;
  const float* kp0 = kT + ((size_t)h << 20);
  for (int t0 = 0; t0 < 1024; t0 += 64) {
    int i = (kc << 10) + t0 + d;   // d doubles as kk for score phase
    float s[8];
#pragma unroll
    for (int j = 0; j < 8; j++) s[j] = 0.f;
#pragma unroll 4
    for (int dd = 0; dd < 64; dd++) {
      float kd = kp0[((size_t)dd << 14) + i];
#pragma unroll
      for (int j = 0; j < 8; j++) s[j] += ql[(grp << 3) + j][dd] * kd;
    }
    __syncthreads();
#pragma unroll
    for (int j = 0; j < 8; j++) {
      int r = (grp << 3) + j;
      pt[d][r] = __expf(s[j] - mrow[r]) * lrow[r];
    }
    __syncthreads();
    const float* vp = qkv + (size_t)((kc << 10) + t0) * 1536 + 1024 + (h << 6) + d;
#pragma unroll 4
    for (int k2 = 0; k2 < 64; k2++) {
      float vv = vp[(size_t)k2 * 1536];
#pragma unroll
      for (int j = 0; j < 8; j++) acc[j] += pt[k2][(grp << 3) + j] * vv;
    }
  }
#pragma unroll
  for (int j = 0; j < 8; j++) {
    int row = rc * 32 + (grp << 3) + j;
    atomicAdd(&kv[((size_t)(h * 256 + row) << 6) + d], acc[j]);
  }
}

// fused: softmax(q@k_l^T) @ B + depthwise-conv(v) -> attn_out(bf16)[i][h*64+d]
// grid (512 qchunks of 32, 8 heads)
__global__ __launch_bounds__(256) void attn1_out(
    const float* __restrict__ qkv, const float* __restrict__ k_l,
    const float* __restrict__ Bm, const float* __restrict__ res_k,
    unsigned short* __restrict__ attn_out)
{
  const int qc = blockIdx.x, h = blockIdx.y, tid = threadIdx.x;
  const int q0 = qc * 32;
  __shared__ float qt[32][64];
  __shared__ float st[32][257];
  __shared__ float rk[33];
  __shared__ float mrow[32], srow[32];
  __shared__ float red[32][8];
  for (int e = tid; e < 2048; e += 256) {
    int r = e >> 6, dd = e & 63;
    qt[r][dd] = qkv[(size_t)(q0 + r) * 1536 + (h << 6) + dd] * 0.125f;
  }
  if (tid < 33) rk[tid] = res_k[h * 33 + tid];
  __syncthreads();
  {
    float kreg[64];
    const float4* kr4 = (const float4*)(k_l + ((size_t)(h * 256 + tid) << 6));
#pragma unroll
    for (int u = 0; u < 16; u++) {
      float4 kv4 = kr4[u];
      kreg[4 * u] = kv4.x; kreg[4 * u + 1] = kv4.y; kreg[4 * u + 2] = kv4.z; kreg[4 * u + 3] = kv4.w;
    }
#pragma unroll 1
    for (int r = 0; r < 32; r++) {
      float s = 0.f;
#pragma unroll
      for (int dd = 0; dd < 64; dd++) s += qt[r][dd] * kreg[dd];
      st[r][tid] = s;
    }
  }
  __syncthreads();
  {
    int r = tid & 31, seg = tid >> 5;
    float mx = -1e30f;
    for (int j = seg * 32; j < seg * 32 + 32; j++) mx = fmaxf(mx, st[r][j]);
    red[r][seg] = mx;
  }
  __syncthreads();
  if (tid < 32) {
    float mx = -1e30f;
#pragma unroll
    for (int s2 = 0; s2 < 8; s2++) mx = fmaxf(mx, red[tid][s2]);
    mrow[tid] = mx;
  }
  __syncthreads();
  {
    int r = tid & 31, seg = tid >> 5;
    float sm = 0.f, mx = mrow[r];
    for (int j = seg * 32; j < seg * 32 + 32; j++) {
      float e = __expf(st[r][j] - mx);
      st[r][j] = e;
      sm += e;
    }
    red[r][seg] = sm;
  }
  __syncthreads();
  if (tid < 32) {
    float sm = 0.f;
#pragma unroll
    for (int s2 = 0; s2 < 8; s2++) sm += red[tid][s2];
    srow[tid] = 1.f / sm;
  }
  __syncthreads();
  const int d = tid & 63, grp = tid >> 6;
  float acc[8];
#pragma unroll
  for (int j = 0; j < 8; j++) acc[j] = 0.f;
  const float* bp = Bm + ((size_t)h << 14) + d;
#pragma unroll 4
  for (int j = 0; j < 256; j++) {
    float bv = bp[(size_t)j << 6];
#pragma unroll
    for (int r8 = 0; r8 < 8; r8++) acc[r8] += st[(grp << 3) + r8][j] * bv;
  }
#pragma unroll 1
  for (int r8 = 0; r8 < 8; r8++) {
    int q = (grp << 3) + r8;
    int i = q0 + q;
    float v = acc[r8] * srow[q];
    float cv = 0.f;
#pragma unroll
    for (int u = 0; u < 33; u++) {
      int ii = i + u - 16;
      if (ii >= 0 && ii < NTOK)
        cv += rk[u] * qkv[(size_t)ii * 1536 + 1024 + (h << 6) + d];
    }
    attn_out[((size_t)i << 9) + (h << 6) + d] = f2bf(v + cv);
  }
}

// final: layernorm row0 -> 4 logits -> sigmoid + cumprod
__global__ __launch_bounds__(256) void final_head(
    const float* __restrict__ hrow, const float* __restrict__ nw, const float* __restrict__ nb,
    const float* __restrict__ cw, const float* __restrict__ cb, float* __restrict__ out)
{
  const int tid = threadIdx.x;
  __shared__ float ln0[512];
  __shared__ float r1[4], r2[4];
  __shared__ float lg[4][4];
  float2 v = ((const float2*)hrow)[tid];
  float sum = v.x + v.y, sq = v.x * v.x + v.y * v.y;
#pragma unroll
  for (int off = 32; off; off >>= 1) { sum += __shfl_xor(sum, off); sq += __shfl_xor(sq, off); }
  if ((tid & 63) == 0) { r1[tid >> 6] = sum; r2[tid >> 6] = sq; }
  __syncthreads();
  sum = r1[0] + r1[1] + r1[2] + r1[3];
  sq  = r2[0] + r2[1] + r2[2] + r2[3];
  float mu = sum * (1.f / 512.f);
  float var = sq * (1.f / 512.f) - mu * mu;
  float rs = rsqrtf(var + 1e-5f);
  ln0[2 * tid]     = (v.x - mu) * rs * nw[2 * tid]     + nb[2 * tid];
  ln0[2 * tid + 1] = (v.y - mu) * rs * nw[2 * tid + 1] + nb[2 * tid + 1];
  __syncthreads();
  float p[4] = {0.f, 0.f, 0.f, 0.f};
  for (int k = tid; k < 512; k += 256) {
    float lv = ln0[k];
#pragma unroll
    for (int c = 0; c < 4; c++) p[c] += lv * cw[k * 4 + c];
  }
#pragma unroll
  for (int off = 32; off; off >>= 1)
#pragma unroll
    for (int c = 0; c < 4; c++) p[c] += __shfl_xor(p[c], off);
  if ((tid & 63) == 0) {
    int w = tid >> 6;
#pragma unroll
    for (int c = 0; c < 4; c++) lg[w][c] = p[c];
  }
  __syncthreads();
  if (tid == 0) {
    float cum = 1.f;
    for (int c = 0; c < 4; c++) {
      float logit = lg[0][c] + lg[1][c] + lg[2][c] + lg[3][c] + cb[c];
      float hz = 1.f / (1.f + __expf(-logit));
      out[c] = hz;
      cum *= (1.f - hz);
      out[4 + c] = cum;
    }
  }
}

// ---------------------------------------------------------------------------
extern "C" void kernel_launch(void* const* d_in, const int* in_sizes, int n_in,
                              void* d_out, int out_size, void* d_ws, size_t ws_size,
                              hipStream_t stream)
{
  (void)in_sizes; (void)n_in; (void)out_size; (void)ws_size;
  const float* x    = (const float*)d_in[0];
  const float* fc_w = (const float*)d_in[1];
  const float* fc_b = (const float*)d_in[2];
  const float* cls  = (const float*)d_in[3];
  const float* nw[2]   = {(const float*)d_in[4],  (const float*)d_in[10]};
  const float* nb[2]   = {(const float*)d_in[5],  (const float*)d_in[11]};
  const float* qkvw[2] = {(const float*)d_in[6],  (const float*)d_in[12]};
  const float* outw[2] = {(const float*)d_in[7],  (const float*)d_in[13]};
  const float* outb[2] = {(const float*)d_in[8],  (const float*)d_in[14]};
  const float* resk[2] = {(const float*)d_in[9],  (const float*)d_in[15]};
  const float* fnw = (const float*)d_in[16];
  const float* fnb = (const float*)d_in[17];
  const float* cw  = (const float*)d_in[18];
  const float* cb  = (const float*)d_in[19];

  float* ws = (float*)d_ws;
  float* h    = ws; ws += (size_t)NTOK * NDIM;
  float* qkv  = ws; ws += (size_t)NTOK * 1536;   // also aliased as xb (bf16) pre-loop
  float* kT   = ws; ws += (size_t)NDIM * NTOK;
  float* q_l  = ws; ws += 8 * 256 * 64;
  float* k_l  = ws; ws += 8 * 256 * 64;
  float* x2   = ws; ws += 8 * 256 * 256;
  float* z0   = ws; ws += 8 * 256 * 256;
  float* z1   = ws; ws += 8 * 256 * 256;
  float* tA   = ws; ws += 8 * 256 * 256;
  float* tB   = ws; ws += 8 * 256 * 256;
  float* tC   = ws; ws += 8 * 256 * 256;
  float* mlp  = ws; ws += 8 * 16 * 256 * 2;
  float* mfin = ws; ws += 8 * 256;
  float* lfin = ws; ws += 8 * 256;
  float* kv   = ws; ws += 8 * 256 * 64;
  float* Bm   = ws; ws += 8 * 256 * 64;
  float* scal = ws; ws += 64;
  unsigned short* actb = (unsigned short*)ws; ws += (size_t)NTOK * NDIM / 2;  // bf16 ln/attn_out
  unsigned short* wT   = (unsigned short*)ws; ws += (1536 * 512) / 2;         // bf16 weight^T
  unsigned short* xb = (unsigned short*)qkv;  // bf16 padded x (16384x1024), dead before qkv use

  // ---- fc + relu: h rows 1..16383 ----
  castpad_x<<<16384, 256, 0, stream>>>(x, xb, (size_t)16383 * 1024);
  transpose_cast<<<dim3(32, 16), 256, 0, stream>>>(fc_w, wT, 1024, 512);
  gemm_bf16<1><<<dim3(4, 128), 256, 0, stream>>>(xb, wT, h + 512, fc_b,
                                                 16384, 512, 1024, 16383);
  cls_copy<<<1, 512, 0, stream>>>(cls, h);

  for (int L = 0; L < 2; L++) {
    layernorm_rows<<<NTOK, 256, 0, stream>>>(h, actb, nw[L], nb[L]);
    transpose_cast<<<dim3(16, 48), 256, 0, stream>>>(qkvw[L], wT, 512, 1536);
    gemm_bf16<0><<<dim3(12, 128), 256, 0, stream>>>(actb, wT, qkv, nullptr,
                                                    NTOK, 1536, 512, NTOK);
    pool_lm<<<512, 256, 0, stream>>>(qkv, q_l, k_l);
    transpose_k<<<dim3(NTOK / 32, 512 / 32), 256, 0, stream>>>(qkv, kT);
    attn2_softmax<<<dim3(256, 8), 256, 0, stream>>>(q_l, k_l, x2);
    hipMemsetAsync(scal, 0, 2 * sizeof(float), stream);
    colrow_max<<<dim3(256, 8), 256, 0, stream>>>(x2, scal);
    zinit<<<2048, 256, 0, stream>>>(x2, z0, scal);
    float* zin = z0; float* zout = z1;
    for (int it = 0; it < 6; it++) {
      bmm_f32<<<dim3(4, 4, 8), 256, 0, stream>>>(x2, zin, tA, 256, 256, 256, 1.f, 0.f);
      eyesub<<<2048, 256, 0, stream>>>(tA, tB, 7.f);
      bmm_f32<<<dim3(4, 4, 8), 256, 0, stream>>>(tA, tB, tC, 256, 256, 256, -1.f, 15.f);
      bmm_f32<<<dim3(4, 4, 8), 256, 0, stream>>>(tA, tC, tB, 256, 256, 256, -1.f, 13.f);
      bmm_f32<<<dim3(4, 4, 8), 256, 0, stream>>>(zin, tB, zout, 256, 256, 256, 0.25f, 0.f);
      float* t = zin; zin = zout; zout = t;
    }
    flash_ml<<<dim3(8, 8, 16), 256, 0, stream>>>(q_l, kT, mlp);
    ml_merge<<<8, 256, 0, stream>>>(mlp, mfin, lfin);
    hipMemsetAsync(kv, 0, (size_t)8 * 256 * 64 * sizeof(float), stream);
    flash_kv<<<dim3(8, 8, 16), 256, 0, stream>>>(q_l, kT, qkv, mfin, lfin, kv);
    bmm_f32<<<dim3(1, 4, 8), 256, 0, stream>>>(zin, kv, Bm, 256, 64, 256, 1.f, 0.f);
    attn1_out<<<dim3(512, 8), 256, 0, stream>>>(qkv, k_l, Bm, resk[L], actb);
    transpose_cast<<<dim3(16, 16), 256, 0, stream>>>(outw[L], wT, 512, 512);
    gemm_bf16<2><<<dim3(4, 128), 256, 0, stream>>>(actb, wT, h, outb[L],
                                                   NTOK, 512, 512, NTOK);
  }
  final_head<<<1, 256, 0, stream>>>(h, fnw, fnb, cw, cb, (float*)d_out);
}

// Round 3
// 2089.081 us; speedup vs baseline: 2.4722x; 1.4969x over previous
//
#include <hip/hip_runtime.h>

#define NTOK 16384
#define NDIM 512
#define STP_LD 280   // ushorts per P row in LDS (16B-aligned, bank-friendly)

typedef __attribute__((ext_vector_type(8))) short short8;
typedef __attribute__((ext_vector_type(4))) float f32x4;

__device__ __forceinline__ unsigned short f2bf(float f) {
  unsigned u = __float_as_uint(f);
  u += 0x7fffu + ((u >> 16) & 1u);
  return (unsigned short)(u >> 16);
}

__device__ __forceinline__ void gload_lds16(const void* g, void* l) {
  __builtin_amdgcn_global_load_lds(
      (const __attribute__((address_space(1))) unsigned int*)(unsigned long long)(g),
      (__attribute__((address_space(3))) unsigned int*)(unsigned long long)(l), 16, 0, 0);
}

// ---------------------------------------------------------------------------
// bf16 MFMA GEMM: C(f32)[M][N] = epi(A(bf16)[M][K] @ Bt(bf16)[N][K]^T)
// 128x128 tile, BK=32, 256 thr (4 waves 2x2), wave does 64x64 via 4x4 mfma
// EPI 0: C=AB   1: C=relu(AB+bias)   2: C+=AB+bias
// ---------------------------------------------------------------------------
template<int EPI>
__global__ __launch_bounds__(256) void gemm_bf16(
    const unsigned short* __restrict__ A, const unsigned short* __restrict__ Bt,
    float* __restrict__ C, const float* __restrict__ bias,
    int M, int N, int K, int Mstore)
{
  __shared__ unsigned short As[128 * 32];
  __shared__ unsigned short Bs[128 * 32];
  const int tid = threadIdx.x;
  const int row0 = blockIdx.y * 128, col0 = blockIdx.x * 128;
  const int wave = tid >> 6, lane = tid & 63;
  const int wm = (wave >> 1) * 64, wn = (wave & 1) * 64;
  const int quad = lane >> 4, m16 = lane & 15;

  const int r0 = tid >> 2;
  const int c8 = (tid & 3) * 8;
  const unsigned short* Ag0 = A + (size_t)(row0 + r0) * K + c8;
  const unsigned short* Ag1 = A + (size_t)(row0 + r0 + 64) * K + c8;
  const unsigned short* Bg0 = Bt + (size_t)(col0 + r0) * K + c8;
  const unsigned short* Bg1 = Bt + (size_t)(col0 + r0 + 64) * K + c8;
  char* AsB = (char*)As;
  char* BsB = (char*)Bs;
  const int wb = wave * 1024;

  f32x4 acc[4][4] = {};
  for (int k0 = 0; k0 < K; k0 += 32) {
    gload_lds16(Ag0 + k0, AsB + wb);
    gload_lds16(Ag1 + k0, AsB + 4096 + wb);
    gload_lds16(Bg0 + k0, BsB + wb);
    gload_lds16(Bg1 + k0, BsB + 4096 + wb);
    __syncthreads();
    short8 af[4], bf[4];
#pragma unroll
    for (int i = 0; i < 4; i++) {
      af[i] = *(const short8*)&As[(wm + i * 16 + m16) * 32 + quad * 8];
      bf[i] = *(const short8*)&Bs[(wn + i * 16 + m16) * 32 + quad * 8];
    }
#pragma unroll
    for (int i = 0; i < 4; i++)
#pragma unroll
      for (int j = 0; j < 4; j++)
        acc[i][j] = __builtin_amdgcn_mfma_f32_16x16x32_bf16(af[i], bf[j], acc[i][j], 0, 0, 0);
    __syncthreads();
  }
#pragma unroll
  for (int i = 0; i < 4; i++) {
#pragma unroll
    for (int r = 0; r < 4; r++) {
      int gr = row0 + wm + i * 16 + quad * 4 + r;
      if (gr < Mstore) {
#pragma unroll
        for (int j = 0; j < 4; j++) {
          int gc = col0 + wn + j * 16 + m16;
          float v = acc[i][j][r];
          if (EPI == 1) { v += bias[gc]; v = fmaxf(v, 0.f); }
          if (EPI == 2) { v += bias[gc] + C[(size_t)gr * N + gc]; }
          C[(size_t)gr * N + gc] = v;
        }
      }
    }
  }
}

// ---------------------------------------------------------------------------
// bf16 MFMA batched (8 heads) 256x256x256 GEMM for pinv.
// A [h][256][256] row-major, Bt [h][256][256] = B^T ([n][k]).
// Writes (optionally): Cn[m][n] = bf16(an*P + bn*I), Ct[n][m] = bf16(at*P + bt*I)
// ---------------------------------------------------------------------------
template<bool WN, bool WT>
__global__ __launch_bounds__(256) void bmm_pinv(
    const unsigned short* __restrict__ A, const unsigned short* __restrict__ Bt,
    unsigned short* __restrict__ Cn, unsigned short* __restrict__ Ct,
    float an, float bn, float at, float bt)
{
  const int hh = blockIdx.z;
  A  += (size_t)hh << 16;
  Bt += (size_t)hh << 16;
  __shared__ unsigned short As[128 * 32];
  __shared__ unsigned short Bs[128 * 32];
  const int tid = threadIdx.x;
  const int row0 = blockIdx.y * 128, col0 = blockIdx.x * 128;
  const int wave = tid >> 6, lane = tid & 63;
  const int wm = (wave >> 1) * 64, wn = (wave & 1) * 64;
  const int quad = lane >> 4, m16 = lane & 15;
  const int r0 = tid >> 2, c8 = (tid & 3) * 8;
  const unsigned short* Ag0 = A + (size_t)(row0 + r0) * 256 + c8;
  const unsigned short* Ag1 = A + (size_t)(row0 + r0 + 64) * 256 + c8;
  const unsigned short* Bg0 = Bt + (size_t)(col0 + r0) * 256 + c8;
  const unsigned short* Bg1 = Bt + (size_t)(col0 + r0 + 64) * 256 + c8;
  char* AsB = (char*)As; char* BsB = (char*)Bs;
  const int wb = wave * 1024;
  f32x4 acc[4][4] = {};
  for (int k0 = 0; k0 < 256; k0 += 32) {
    gload_lds16(Ag0 + k0, AsB + wb);
    gload_lds16(Ag1 + k0, AsB + 4096 + wb);
    gload_lds16(Bg0 + k0, BsB + wb);
    gload_lds16(Bg1 + k0, BsB + 4096 + wb);
    __syncthreads();
    short8 af[4], bf[4];
#pragma unroll
    for (int i = 0; i < 4; i++) {
      af[i] = *(const short8*)&As[(wm + i * 16 + m16) * 32 + quad * 8];
      bf[i] = *(const short8*)&Bs[(wn + i * 16 + m16) * 32 + quad * 8];
    }
#pragma unroll
    for (int i = 0; i < 4; i++)
#pragma unroll
      for (int j = 0; j < 4; j++)
        acc[i][j] = __builtin_amdgcn_mfma_f32_16x16x32_bf16(af[i], bf[j], acc[i][j], 0, 0, 0);
    __syncthreads();
  }
  unsigned short* CnH = Cn + ((size_t)hh << 16);
  unsigned short* CtH = Ct + ((size_t)hh << 16);
#pragma unroll
  for (int i = 0; i < 4; i++) {
#pragma unroll
    for (int r = 0; r < 4; r++) {
      int gr = row0 + wm + i * 16 + quad * 4 + r;
#pragma unroll
      for (int j = 0; j < 4; j++) {
        int gc = col0 + wn + j * 16 + m16;
        float p = acc[i][j][r];
        float diag = (gr == gc) ? 1.f : 0.f;
        if (WN) CnH[(size_t)gr * 256 + gc] = f2bf(an * p + bn * diag);
        if (WT) CtH[(size_t)gc * 256 + gr] = f2bf(at * p + bt * diag);
      }
    }
  }
}

// cast fp32 -> bf16, pad (zero) past nvalid elements
__global__ void castpad_x(const float* __restrict__ x, unsigned short* __restrict__ xb,
                          size_t nvalid) {
  size_t i4 = ((size_t)blockIdx.x * 256 + threadIdx.x) * 4;
  float4 v = make_float4(0.f, 0.f, 0.f, 0.f);
  if (i4 < nvalid) v = *(const float4*)(x + i4);
  ushort4 o;
  o.x = f2bf(v.x); o.y = f2bf(v.y); o.z = f2bf(v.z); o.w = f2bf(v.w);
  *(ushort4*)(xb + i4) = o;
}

// in fp32 [R][C] -> out bf16 [C][R]
__global__ __launch_bounds__(256) void transpose_cast(
    const float* __restrict__ in, unsigned short* __restrict__ out, int R, int C)
{
  __shared__ float tile[32][33];
  int r0 = blockIdx.x * 32, c0 = blockIdx.y * 32;
  int tx = threadIdx.x & 31, ty = threadIdx.x >> 5;
  for (int yy = ty; yy < 32; yy += 8)
    tile[yy][tx] = in[(size_t)(r0 + yy) * C + c0 + tx];
  __syncthreads();
  for (int yy = ty; yy < 32; yy += 8)
    out[(size_t)(c0 + yy) * R + r0 + tx] = f2bf(tile[tx][yy]);
}

// qb = bf16(q * 0.125), q = qkv[:, 0:512]
__global__ void cast_q(const float* __restrict__ qkv, unsigned short* __restrict__ qb) {
  size_t e4 = ((size_t)blockIdx.x * 256 + threadIdx.x) * 4;
  int i = (int)(e4 >> 9), c = (int)(e4 & 511);
  const float* p = qkv + (size_t)i * 1536 + c;
  float4 v = *(const float4*)p;
  ushort4 o;
  o.x = f2bf(v.x * 0.125f); o.y = f2bf(v.y * 0.125f);
  o.z = f2bf(v.z * 0.125f); o.w = f2bf(v.w * 0.125f);
  *(ushort4*)(qb + e4) = o;
}

__global__ void cast_bf2f(const unsigned short* __restrict__ in, float* __restrict__ out) {
  int i = blockIdx.x * 256 + threadIdx.x;
  out[i] = __uint_as_float((unsigned)in[i] << 16);
}

// ---------------------------------------------------------------------------
// fp32 batched GEMM (pinv polish): C = alpha*(A@B) + beta*I
// ---------------------------------------------------------------------------
__global__ __launch_bounds__(256) void bmm_f32(
    const float* __restrict__ A, const float* __restrict__ B, float* __restrict__ C,
    int M, int N, int K, float alpha, float beta)
{
  const int h = blockIdx.z;
  A += (size_t)h * M * K; B += (size_t)h * K * N; C += (size_t)h * M * N;
  __shared__ float As[16][64];
  __shared__ float Bs[16][64];
  const int tid = threadIdx.x;
  const int row0 = blockIdx.y * 64, col0 = blockIdx.x * 64;
  const int ty = tid >> 4, tx = tid & 15;
  const int ar = tid >> 2, ac = (tid & 3) << 2;
  const int bk = tid >> 4, bj = (tid & 15) << 2;
  float acc[4][4] = {};
  for (int k0 = 0; k0 < K; k0 += 16) {
    float4 a = *(const float4*)(A + (size_t)(row0 + ar) * K + k0 + ac);
    As[ac + 0][ar] = a.x; As[ac + 1][ar] = a.y; As[ac + 2][ar] = a.z; As[ac + 3][ar] = a.w;
    *(float4*)&Bs[bk][bj] = *(const float4*)(B + (size_t)(k0 + bk) * N + col0 + bj);
    __syncthreads();
#pragma unroll
    for (int kk = 0; kk < 16; kk++) {
      float4 av = *(float4*)&As[kk][ty << 2];
      float4 bv = *(float4*)&Bs[kk][tx << 2];
      float a4[4] = {av.x, av.y, av.z, av.w};
      float b4[4] = {bv.x, bv.y, bv.z, bv.w};
#pragma unroll
      for (int ii = 0; ii < 4; ii++)
#pragma unroll
        for (int jj = 0; jj < 4; jj++) acc[ii][jj] += a4[ii] * b4[jj];
    }
    __syncthreads();
  }
#pragma unroll
  for (int ii = 0; ii < 4; ii++) {
    int gr = row0 + (ty << 2) + ii;
#pragma unroll
    for (int jj = 0; jj < 4; jj++) {
      int gc = col0 + (tx << 2) + jj;
      float v = alpha * acc[ii][jj];
      if (gr == gc) v += beta;
      C[(size_t)gr * N + gc] = v;
    }
  }
}

__global__ void eyesub(const float* __restrict__ in, float* __restrict__ out, float c) {
  int idx = blockIdx.x * 256 + threadIdx.x;
  int i = (idx >> 8) & 255, j = idx & 255;
  out[idx] = ((i == j) ? c : 0.f) - in[idx];
}

__global__ void cls_copy(const float* __restrict__ cls, float* __restrict__ h) {
  int t = threadIdx.x;
  if (t < 512) h[t] = cls[t];
}

// per-row layernorm over 512, writes bf16
__global__ __launch_bounds__(256) void layernorm_rows(
    const float* __restrict__ x, unsigned short* __restrict__ y,
    const float* __restrict__ w, const float* __restrict__ b)
{
  const int row = blockIdx.x, tid = threadIdx.x;
  const float* xr = x + (size_t)row * NDIM;
  float2 v = ((const float2*)xr)[tid];
  float sum = v.x + v.y, sq = v.x * v.x + v.y * v.y;
#pragma unroll
  for (int off = 32; off; off >>= 1) { sum += __shfl_xor(sum, off); sq += __shfl_xor(sq, off); }
  __shared__ float r1[4], r2[4];
  if ((tid & 63) == 0) { r1[tid >> 6] = sum; r2[tid >> 6] = sq; }
  __syncthreads();
  sum = r1[0] + r1[1] + r1[2] + r1[3];
  sq  = r2[0] + r2[1] + r2[2] + r2[3];
  float mu = sum * (1.f / 512.f);
  float var = sq * (1.f / 512.f) - mu * mu;
  float rs = rsqrtf(var + 1e-5f);
  float a = (v.x - mu) * rs * w[2 * tid]     + b[2 * tid];
  float c = (v.y - mu) * rs * w[2 * tid + 1] + b[2 * tid + 1];
  ((unsigned*)(y + (size_t)row * NDIM))[tid] = (unsigned)f2bf(a) | ((unsigned)f2bf(c) << 16);
}

// landmark pooling (q scaled by 1/8); also bf16 copy of k_l
__global__ void pool_lm(const float* __restrict__ qkv,
                        float* __restrict__ q_l, float* __restrict__ k_l,
                        unsigned short* __restrict__ k_lb)
{
  int idx = blockIdx.x * 256 + threadIdx.x;          // (h,j,d) 8*256*64
  int d = idx & 63, j = (idx >> 6) & 255, h = idx >> 14;
  const float* bq = qkv + (size_t)(j << 6) * 1536 + (h << 6) + d;
  float sq = 0.f, sk = 0.f;
  for (int u = 0; u < 64; u++) { sq += bq[(size_t)u * 1536]; sk += bq[(size_t)u * 1536 + 512]; }
  float kl = sk * (1.f / 64.f);
  q_l[idx] = sq * (1.f / 64.f) * 0.125f;
  k_l[idx] = kl;
  k_lb[idx] = f2bf(kl);
}

// kT[h*64+d][i] = qkv[i][512 + h*64+d]
__global__ __launch_bounds__(256) void transpose_k(const float* __restrict__ qkv,
                                                   float* __restrict__ kT)
{
  __shared__ float tile[32][33];
  int i0 = blockIdx.x * 32, c0 = blockIdx.y * 32;
  int tx = threadIdx.x & 31, ty = threadIdx.x >> 5;
  for (int yy = ty; yy < 32; yy += 8)
    tile[yy][tx] = qkv[(size_t)(i0 + yy) * 1536 + 512 + c0 + tx];
  __syncthreads();
  for (int yy = ty; yy < 32; yy += 8)
    kT[(size_t)(c0 + yy) * NTOK + i0 + tx] = tile[tx][yy];
}

// attn2 = softmax(q_l @ k_l^T) rows; fp32 + bf16 outputs
__global__ __launch_bounds__(256) void attn2_softmax(
    const float* __restrict__ q_l, const float* __restrict__ k_l,
    float* __restrict__ x2, unsigned short* __restrict__ x2b)
{
  int row = blockIdx.x, h = blockIdx.y, j = threadIdx.x;
  __shared__ float qrow[64];
  __shared__ float red[4];
  if (j < 64) qrow[j] = q_l[(size_t)(h * 256 + row) * 64 + j];
  __syncthreads();
  const float* kr = k_l + (size_t)(h * 256 + j) * 64;
  float s = 0.f;
#pragma unroll 8
  for (int d = 0; d < 64; d++) s += qrow[d] * kr[d];
  float m = s;
#pragma unroll
  for (int off = 32; off; off >>= 1) m = fmaxf(m, __shfl_xor(m, off));
  if ((j & 63) == 0) red[j >> 6] = m;
  __syncthreads();
  m = fmaxf(fmaxf(red[0], red[1]), fmaxf(red[2], red[3]));
  __syncthreads();
  float e = __expf(s - m), l = e;
#pragma unroll
  for (int off = 32; off; off >>= 1) l += __shfl_xor(l, off);
  if ((j & 63) == 0) red[j >> 6] = l;
  __syncthreads();
  l = red[0] + red[1] + red[2] + red[3];
  float val = e / l;
  size_t o = ((size_t)(h * 256 + row) << 8) + j;
  x2[o] = val;
  x2b[o] = f2bf(val);
}

__global__ __launch_bounds__(256) void colrow_max(const float* __restrict__ x2,
                                                  float* __restrict__ scal)
{
  int t = threadIdx.x, r = blockIdx.x, h = blockIdx.y;
  float rv = x2[((size_t)(h * 256 + r) << 8) + t];
  float cv = x2[((size_t)(h * 256 + t) << 8) + r];
#pragma unroll
  for (int off = 32; off; off >>= 1) { rv += __shfl_xor(rv, off); cv += __shfl_xor(cv, off); }
  __shared__ float rr[4], cc[4];
  if ((t & 63) == 0) { rr[t >> 6] = rv; cc[t >> 6] = cv; }
  __syncthreads();
  if (t == 0) {
    float rs = rr[0] + rr[1] + rr[2] + rr[3];
    float cs = cc[0] + cc[1] + cc[2] + cc[3];
    atomicMax((unsigned int*)&scal[0], __float_as_uint(rs));
    atomicMax((unsigned int*)&scal[1], __float_as_uint(cs));
  }
}

// z0 (bf16, [j][i]) and z0^T (bf16, [i][j]) from x2
__global__ void zinit_bf(const float* __restrict__ x2, unsigned short* __restrict__ zb,
                         unsigned short* __restrict__ zTb, const float* __restrict__ scal)
{
  int idx = blockIdx.x * 256 + threadIdx.x;
  int hh = idx >> 16, i = (idx >> 8) & 255, j = idx & 255;
  float den = scal[0] * scal[1];
  float val = x2[idx] / den;
  unsigned short b = f2bf(val);
  zTb[idx] = b;
  zb[(hh << 16) + (j << 8) + i] = b;
}

// attn3 softmax stats (m,l) partials: grid (8 heads, 8 rowchunks, 16 keychunks)
__global__ __launch_bounds__(256) void flash_ml(
    const float* __restrict__ q_l, const float* __restrict__ kT, float* __restrict__ mlp)
{
  const int h = blockIdx.x, rc = blockIdx.y, kc = blockIdx.z, tid = threadIdx.x;
  __shared__ float ql[32][64];
  __shared__ float redm[32][4], redl[32][4];
  const float* qsrc = q_l + ((size_t)(h * 256 + rc * 32) << 6);
  for (int e = tid; e < 2048; e += 256) (&ql[0][0])[e] = qsrc[e];
  __syncthreads();
  float m[32], l[32];
#pragma unroll
  for (int r = 0; r < 32; r++) { m[r] = -1e30f; l[r] = 0.f; }
  const float* kp0 = kT + ((size_t)h << 20);
  for (int step = 0; step < 4; step++) {
    int i = (kc << 10) + (step << 8) + tid;
    float s[32];
#pragma unroll
    for (int r = 0; r < 32; r++) s[r] = 0.f;
#pragma unroll 4
    for (int dd = 0; dd < 64; dd++) {
      float kd = kp0[((size_t)dd << 14) + i];
#pragma unroll
      for (int r = 0; r < 32; r++) s[r] += ql[r][dd] * kd;
    }
#pragma unroll
    for (int r = 0; r < 32; r++) {
      float mn = fmaxf(m[r], s[r]);
      l[r] = l[r] * __expf(m[r] - mn) + __expf(s[r] - mn);
      m[r] = mn;
    }
  }
#pragma unroll 1
  for (int r = 0; r < 32; r++) {
    float mm = m[r], ll = l[r];
#pragma unroll
    for (int off = 32; off; off >>= 1) {
      float om = __shfl_xor(mm, off), ol = __shfl_xor(ll, off);
      float mn = fmaxf(mm, om);
      ll = ll * __expf(mm - mn) + ol * __expf(om - mn);
      mm = mn;
    }
    if ((tid & 63) == 0) { redm[r][tid >> 6] = mm; redl[r][tid >> 6] = ll; }
  }
  __syncthreads();
  if (tid < 32) {
    float mm = -1e30f, ll = 0.f;
#pragma unroll
    for (int w = 0; w < 4; w++) {
      float om = redm[tid][w], ol = redl[tid][w];
      float mn = fmaxf(mm, om);
      ll = ll * __expf(mm - mn) + ol * __expf(om - mn);
      mm = mn;
    }
    int o = ((h * 16 + kc) * 256 + rc * 32 + tid) * 2;
    mlp[o] = mm; mlp[o + 1] = ll;
  }
}

__global__ void ml_merge(const float* __restrict__ mlp,
                         float* __restrict__ mfin, float* __restrict__ lfin)
{
  int h = blockIdx.x, r = threadIdx.x;
  float m = -1e30f, l = 0.f;
  for (int kc = 0; kc < 16; kc++) {
    int o = ((h * 16 + kc) * 256 + r) * 2;
    float m2 = mlp[o], l2 = mlp[o + 1];
    float mn = fmaxf(m, m2);
    l = l * __expf(m - mn) + l2 * __expf(m2 - mn);
    m = mn;
  }
  mfin[h * 256 + r] = m;
  lfin[h * 256 + r] = l;
}

// kv += P_chunk @ V_chunk  (attn3 @ v), grid (8, 8, 16)
__global__ __launch_bounds__(256) void flash_kv(
    const float* __restrict__ q_l, const float* __restrict__ kT,
    const float* __restrict__ qkv, const float* __restrict__ mfin,
    const float* __restrict__ lfin, float* __restrict__ kv)
{
  const int h = blockIdx.x, rc = blockIdx.y, kc = blockIdx.z, tid = threadIdx.x;
  const int d = tid & 63, grp = tid >> 6;
  __shared__ float ql[32][64];
  __shared__ float pt[64][33];
  __shared__ float mrow[32], lrow[32];
  const float* qsrc = q_l + ((size_t)(h * 256 + rc * 32) << 6);
  for (int e = tid; e < 2048; e += 256) (&ql[0][0])[e] = qsrc[e];
  if (tid < 32) {
    mrow[tid] = mfin[h * 256 + rc * 32 + tid];
    lrow[tid] = 1.f / lfin[h * 256 + rc * 32 + tid];
  }
  __syncthreads();
  float acc[8];
#pragma unroll
  for (int j = 0; j < 8; j++) acc[j] = 0.f;
  const float* kp0 = kT + ((size_t)h << 20);
  for (int t0 = 0; t0 < 1024; t0 += 64) {
    int i = (kc << 10) + t0 + d;
    float s[8];
#pragma unroll
    for (int j = 0; j < 8; j++) s[j] = 0.f;
#pragma unroll 4
    for (int dd = 0; dd < 64; dd++) {
      float kd = kp0[((size_t)dd << 14) + i];
#pragma unroll
      for (int j = 0; j < 8; j++) s[j] += ql[(grp << 3) + j][dd] * kd;
    }
    __syncthreads();
#pragma unroll
    for (int j = 0; j < 8; j++) {
      int r = (grp << 3) + j;
      pt[d][r] = __expf(s[j] - mrow[r]) * lrow[r];
    }
    __syncthreads();
    const float* vp = qkv + (size_t)((kc << 10) + t0) * 1536 + 1024 + (h << 6) + d;
#pragma unroll 4
    for (int k2 = 0; k2 < 64; k2++) {
      float vv = vp[(size_t)k2 * 1536];
#pragma unroll
      for (int j = 0; j < 8; j++) acc[j] += pt[k2][(grp << 3) + j] * vv;
    }
  }
#pragma unroll
  for (int j = 0; j < 8; j++) {
    int row = rc * 32 + (grp << 3) + j;
    atomicAdd(&kv[((size_t)(h * 256 + row) << 6) + d], acc[j]);
  }
}

// BmT[h][d][j] = sum_k zf[h][j][k] * kv[h][k][d]  (bf16 out)
__global__ __launch_bounds__(256) void bmt_kernel(
    const float* __restrict__ zf, const float* __restrict__ kv,
    unsigned short* __restrict__ BmT)
{
  const int jb = blockIdx.x, hh = blockIdx.y, tid = threadIdx.x;
  __shared__ float zt[64 * 256];
  const float* zsrc = zf + ((size_t)hh << 16) + (size_t)(jb * 64) * 256;
  for (int rep = 0; rep < 16; rep++) {
    int e4 = (rep * 256 + tid) * 4;
    *(float4*)&zt[e4] = *(const float4*)(zsrc + e4);
  }
  __syncthreads();
  const int d = tid & 63, jg = tid >> 6;
  const float* kvh = kv + ((size_t)hh << 14) + d;
  float acc[16];
#pragma unroll
  for (int u = 0; u < 16; u++) acc[u] = 0.f;
  for (int k0 = 0; k0 < 256; k0 += 8) {
    float kv8[8];
#pragma unroll
    for (int u = 0; u < 8; u++) kv8[u] = kvh[(size_t)(k0 + u) << 6];
#pragma unroll
    for (int jj = 0; jj < 16; jj++) {
      const float* zr = &zt[(jg * 16 + jj) * 256 + k0];
#pragma unroll
      for (int u = 0; u < 8; u++) acc[jj] += zr[u] * kv8[u];
    }
  }
  unsigned short* ob = BmT + ((size_t)hh << 14) + (size_t)d * 256 + jb * 64 + jg * 16;
#pragma unroll
  for (int jj = 0; jj < 16; jj++) ob[jj] = f2bf(acc[jj]);
}

// ---------------------------------------------------------------------------
// fused attn1: softmax(q@k_l^T) @ Bm + depthwise-conv(v) -> attn_out bf16
// MFMA for both GEMMs; softmax in C-fragment registers. grid (512, 8)
// ---------------------------------------------------------------------------
__global__ __launch_bounds__(256) void attn1_out(
    const unsigned short* __restrict__ qb, const unsigned short* __restrict__ k_lb,
    const unsigned short* __restrict__ BmT, const float* __restrict__ qkv,
    const float* __restrict__ res_k, unsigned short* __restrict__ attn_out)
{
  const int qc = blockIdx.x, h = blockIdx.y, tid = threadIdx.x;
  const int q0 = qc * 32;
  const int wave = tid >> 6, lane = tid & 63;
  const int quad = lane >> 4, m16 = lane & 15;

  __shared__ unsigned short stp[32 * STP_LD];
  __shared__ float v_lds[64 * 68];
  __shared__ float redm[4][32], redl[4][32];
  __shared__ float rk[33];

  if (tid < 33) rk[tid] = res_k[h * 33 + tid];

  // v tile: global rows q0-16 .. q0+47 (zero-padded)
  {
    int vr = tid >> 2, seg = tid & 3;
    int gi = q0 - 16 + vr;
    const float* vp = qkv + (size_t)gi * 1536 + 1024 + (h << 6) + seg * 16;
    bool ok = (gi >= 0 && gi < NTOK);
#pragma unroll
    for (int u = 0; u < 4; u++) {
      float4 vv = ok ? *(const float4*)(vp + 4 * u) : make_float4(0.f, 0.f, 0.f, 0.f);
      *(float4*)&v_lds[vr * 68 + seg * 16 + 4 * u] = vv;
    }
  }

  // phase 1: S tiles. wave owns cols wave*64..+64, all 32 rows.
  f32x4 acc1[2][4] = {};
  {
    const unsigned short* qbase = qb + (size_t)q0 * 512 + (h << 6);
    const unsigned short* kbase = k_lb + ((size_t)h << 14) + (size_t)(wave * 64) * 64;
#pragma unroll
    for (int kc = 0; kc < 2; kc++) {
      short8 aq[2], bk[4];
#pragma unroll
      for (int i = 0; i < 2; i++)
        aq[i] = *(const short8*)(qbase + (size_t)(i * 16 + m16) * 512 + kc * 32 + quad * 8);
#pragma unroll
      for (int n = 0; n < 4; n++)
        bk[n] = *(const short8*)(kbase + (size_t)(n * 16 + m16) * 64 + kc * 32 + quad * 8);
#pragma unroll
      for (int i = 0; i < 2; i++)
#pragma unroll
        for (int n = 0; n < 4; n++)
          acc1[i][n] = __builtin_amdgcn_mfma_f32_16x16x32_bf16(aq[i], bk[n], acc1[i][n], 0, 0, 0);
    }
  }
  // softmax: per-wave partial row max via shfl over 16-lane col groups
#pragma unroll
  for (int i = 0; i < 2; i++) {
#pragma unroll
    for (int e = 0; e < 4; e++) {
      float mx = fmaxf(fmaxf(acc1[i][0][e], acc1[i][1][e]), fmaxf(acc1[i][2][e], acc1[i][3][e]));
      mx = fmaxf(mx, __shfl_xor(mx, 1));
      mx = fmaxf(mx, __shfl_xor(mx, 2));
      mx = fmaxf(mx, __shfl_xor(mx, 4));
      mx = fmaxf(mx, __shfl_xor(mx, 8));
      if (m16 == 0) redm[wave][i * 16 + quad * 4 + e] = mx;
    }
  }
  __syncthreads();
#pragma unroll
  for (int i = 0; i < 2; i++) {
#pragma unroll
    for (int e = 0; e < 4; e++) {
      int r = i * 16 + quad * 4 + e;
      float gm = fmaxf(fmaxf(redm[0][r], redm[1][r]), fmaxf(redm[2][r], redm[3][r]));
      float s = 0.f;
#pragma unroll
      for (int n = 0; n < 4; n++) {
        float ev = __expf(acc1[i][n][e] - gm);
        acc1[i][n][e] = ev;
        s += ev;
      }
      s += __shfl_xor(s, 1); s += __shfl_xor(s, 2);
      s += __shfl_xor(s, 4); s += __shfl_xor(s, 8);
      if (m16 == 0) redl[wave][r] = s;
    }
  }
  // write unnormalized P (bf16) to LDS in A-frag-friendly layout
#pragma unroll
  for (int i = 0; i < 2; i++)
#pragma unroll
    for (int n = 0; n < 4; n++) {
      int col = wave * 64 + n * 16 + m16;
#pragma unroll
      for (int e = 0; e < 4; e++)
        stp[(i * 16 + quad * 4 + e) * STP_LD + col] = f2bf(acc1[i][n][e]);
    }
  __syncthreads();

  // phase 3: O = P @ BmT^T. wave: rows (wave&1)*16, cols (wave>>1)*32 + {0,16}
  const int mi3 = (wave & 1) * 16;
  const int nbase = (wave >> 1) * 32;
  f32x4 acc3[2] = {};
  {
    const unsigned short* bbase = BmT + ((size_t)h << 14);
#pragma unroll
    for (int kc = 0; kc < 8; kc++) {
      short8 ap = *(const short8*)&stp[(mi3 + m16) * STP_LD + kc * 32 + quad * 8];
#pragma unroll
      for (int t = 0; t < 2; t++) {
        short8 bp = *(const short8*)(bbase + (size_t)(nbase + t * 16 + m16) * 256 + kc * 32 + quad * 8);
        acc3[t] = __builtin_amdgcn_mfma_f32_16x16x32_bf16(ap, bp, acc3[t], 0, 0, 0);
      }
    }
  }
  // epilogue: normalize + conv residual + store
#pragma unroll
  for (int t = 0; t < 2; t++) {
    int d = nbase + t * 16 + m16;
#pragma unroll
    for (int e = 0; e < 4; e++) {
      int lr = mi3 + quad * 4 + e;
      float l = redl[0][lr] + redl[1][lr] + redl[2][lr] + redl[3][lr];
      float v = acc3[t][e] / l;
      float cv = 0.f;
#pragma unroll
      for (int u = 0; u < 33; u++) cv += rk[u] * v_lds[(lr + u) * 68 + d];
      int gi = q0 + lr;
      attn_out[((size_t)gi << 9) + (h << 6) + d] = f2bf(v + cv);
    }
  }
}

// final: layernorm row0 -> 4 logits -> sigmoid + cumprod
__global__ __launch_bounds__(256) void final_head(
    const float* __restrict__ hrow, const float* __restrict__ nw, const float* __restrict__ nb,
    const float* __restrict__ cw, const float* __restrict__ cb, float* __restrict__ out)
{
  const int tid = threadIdx.x;
  __shared__ float ln0[512];
  __shared__ float r1[4], r2[4];
  __shared__ float lg[4][4];
  float2 v = ((const float2*)hrow)[tid];
  float sum = v.x + v.y, sq = v.x * v.x + v.y * v.y;
#pragma unroll
  for (int off = 32; off; off >>= 1) { sum += __shfl_xor(sum, off); sq += __shfl_xor(sq, off); }
  if ((tid & 63) == 0) { r1[tid >> 6] = sum; r2[tid >> 6] = sq; }
  __syncthreads();
  sum = r1[0] + r1[1] + r1[2] + r1[3];
  sq  = r2[0] + r2[1] + r2[2] + r2[3];
  float mu = sum * (1.f / 512.f);
  float var = sq * (1.f / 512.f) - mu * mu;
  float rs = rsqrtf(var + 1e-5f);
  ln0[2 * tid]     = (v.x - mu) * rs * nw[2 * tid]     + nb[2 * tid];
  ln0[2 * tid + 1] = (v.y - mu) * rs * nw[2 * tid + 1] + nb[2 * tid + 1];
  __syncthreads();
  float p[4] = {0.f, 0.f, 0.f, 0.f};
  for (int k = tid; k < 512; k += 256) {
    float lv = ln0[k];
#pragma unroll
    for (int c = 0; c < 4; c++) p[c] += lv * cw[k * 4 + c];
  }
#pragma unroll
  for (int off = 32; off; off >>= 1)
#pragma unroll
    for (int c = 0; c < 4; c++) p[c] += __shfl_xor(p[c], off);
  if ((tid & 63) == 0) {
    int w = tid >> 6;
#pragma unroll
    for (int c = 0; c < 4; c++) lg[w][c] = p[c];
  }
  __syncthreads();
  if (tid == 0) {
    float cum = 1.f;
    for (int c = 0; c < 4; c++) {
      float logit = lg[0][c] + lg[1][c] + lg[2][c] + lg[3][c] + cb[c];
      float hz = 1.f / (1.f + __expf(-logit));
      out[c] = hz;
      cum *= (1.f - hz);
      out[4 + c] = cum;
    }
  }
}

// ---------------------------------------------------------------------------
extern "C" void kernel_launch(void* const* d_in, const int* in_sizes, int n_in,
                              void* d_out, int out_size, void* d_ws, size_t ws_size,
                              hipStream_t stream)
{
  (void)in_sizes; (void)n_in; (void)out_size; (void)ws_size;
  const float* x    = (const float*)d_in[0];
  const float* fc_w = (const float*)d_in[1];
  const float* fc_b = (const float*)d_in[2];
  const float* cls  = (const float*)d_in[3];
  const float* nw[2]   = {(const float*)d_in[4],  (const float*)d_in[10]};
  const float* nb[2]   = {(const float*)d_in[5],  (const float*)d_in[11]};
  const float* qkvw[2] = {(const float*)d_in[6],  (const float*)d_in[12]};
  const float* outw[2] = {(const float*)d_in[7],  (const float*)d_in[13]};
  const float* outb[2] = {(const float*)d_in[8],  (const float*)d_in[14]};
  const float* resk[2] = {(const float*)d_in[9],  (const float*)d_in[15]};
  const float* fnw = (const float*)d_in[16];
  const float* fnb = (const float*)d_in[17];
  const float* cw  = (const float*)d_in[18];
  const float* cb  = (const float*)d_in[19];

  float* ws = (float*)d_ws;
  float* h    = ws; ws += (size_t)NTOK * NDIM;
  float* qkv  = ws; ws += (size_t)NTOK * 1536;   // aliased as xb (bf16) pre-loop
  float* kT   = ws; ws += (size_t)NDIM * NTOK;
  float* q_l  = ws; ws += 8 * 256 * 64;
  float* k_l  = ws; ws += 8 * 256 * 64;
  float* x2   = ws; ws += 8 * 256 * 256;
  float* zf   = ws; ws += 8 * 256 * 256;        // fp32 z (polish in)
  float* zfin = ws; ws += 8 * 256 * 256;        // fp32 z (polish out)
  float* tA   = ws; ws += 8 * 256 * 256;
  float* tB   = ws; ws += 8 * 256 * 256;
  float* tC   = ws; ws += 8 * 256 * 256;
  float* mlp  = ws; ws += 8 * 16 * 256 * 2;
  float* mfin = ws; ws += 8 * 256;
  float* lfin = ws; ws += 8 * 256;
  float* kv   = ws; ws += 8 * 256 * 64;
  float* scal = ws; ws += 64;
  unsigned short* actb = (unsigned short*)ws; ws += (size_t)NTOK * NDIM / 2;
  unsigned short* wT   = (unsigned short*)ws; ws += (1536 * 512) / 2;
  unsigned short* qb   = (unsigned short*)ws; ws += (size_t)NTOK * NDIM / 2;
  unsigned short* k_lb = (unsigned short*)ws; ws += (8 * 256 * 64) / 2;
  unsigned short* x2b  = (unsigned short*)ws; ws += (8 * 256 * 256) / 2;
  unsigned short* zb0  = (unsigned short*)ws; ws += (8 * 256 * 256) / 2;
  unsigned short* zb1  = (unsigned short*)ws; ws += (8 * 256 * 256) / 2;
  unsigned short* zT0  = (unsigned short*)ws; ws += (8 * 256 * 256) / 2;
  unsigned short* zT1  = (unsigned short*)ws; ws += (8 * 256 * 256) / 2;
  unsigned short* xzb  = (unsigned short*)ws; ws += (8 * 256 * 256) / 2;
  unsigned short* t1T  = (unsigned short*)ws; ws += (8 * 256 * 256) / 2;
  unsigned short* t2T  = (unsigned short*)ws; ws += (8 * 256 * 256) / 2;
  unsigned short* t3T  = (unsigned short*)ws; ws += (8 * 256 * 256) / 2;
  unsigned short* BmT  = (unsigned short*)ws; ws += (8 * 64 * 256) / 2;
  unsigned short* xb = (unsigned short*)qkv;   // bf16 padded x, dead before qkv use

  unsigned short* zbp[2] = {zb0, zb1};
  unsigned short* zTp[2] = {zT0, zT1};

  // ---- fc + relu ----
  castpad_x<<<16384, 256, 0, stream>>>(x, xb, (size_t)16383 * 1024);
  transpose_cast<<<dim3(32, 16), 256, 0, stream>>>(fc_w, wT, 1024, 512);
  gemm_bf16<1><<<dim3(4, 128), 256, 0, stream>>>(xb, wT, h + 512, fc_b,
                                                 16384, 512, 1024, 16383);
  cls_copy<<<1, 512, 0, stream>>>(cls, h);

  for (int L = 0; L < 2; L++) {
    layernorm_rows<<<NTOK, 256, 0, stream>>>(h, actb, nw[L], nb[L]);
    transpose_cast<<<dim3(16, 48), 256, 0, stream>>>(qkvw[L], wT, 512, 1536);
    gemm_bf16<0><<<dim3(12, 128), 256, 0, stream>>>(actb, wT, qkv, nullptr,
                                                    NTOK, 1536, 512, NTOK);
    cast_q<<<8192, 256, 0, stream>>>(qkv, qb);
    pool_lm<<<512, 256, 0, stream>>>(qkv, q_l, k_l, k_lb);
    transpose_k<<<dim3(NTOK / 32, 512 / 32), 256, 0, stream>>>(qkv, kT);
    attn2_softmax<<<dim3(256, 8), 256, 0, stream>>>(q_l, k_l, x2, x2b);
    hipMemsetAsync(scal, 0, 2 * sizeof(float), stream);
    colrow_max<<<dim3(256, 8), 256, 0, stream>>>(x2, scal);
    zinit_bf<<<2048, 256, 0, stream>>>(x2, zbp[0], zTp[0], scal);

    // 5 bf16 Newton iterations (4 MFMA GEMMs each, eyesub folded, B born transposed)
    int cur = 0;
    dim3 pg(2, 2, 8);
    for (int it = 0; it < 5; it++) {
      bmm_pinv<true,  true><<<pg, 256, 0, stream>>>(x2b, zTp[cur], xzb, t1T, 1.f, 0.f, -1.f, 7.f);
      bmm_pinv<false, true><<<pg, 256, 0, stream>>>(xzb, t1T, xzb, t2T, 0.f, 0.f, -1.f, 15.f);
      bmm_pinv<false, true><<<pg, 256, 0, stream>>>(xzb, t2T, xzb, t3T, 0.f, 0.f, -1.f, 13.f);
      bmm_pinv<true,  true><<<pg, 256, 0, stream>>>(zbp[cur], t3T, zbp[cur ^ 1], zTp[cur ^ 1],
                                                    0.25f, 0.f, 0.25f, 0.f);
      cur ^= 1;
    }
    // fp32 polish iteration (Newton quadratic convergence erases bf16 noise)
    cast_bf2f<<<2048, 256, 0, stream>>>(zbp[cur], zf);
    bmm_f32<<<dim3(4, 4, 8), 256, 0, stream>>>(x2, zf, tA, 256, 256, 256, 1.f, 0.f);
    eyesub<<<2048, 256, 0, stream>>>(tA, tB, 7.f);
    bmm_f32<<<dim3(4, 4, 8), 256, 0, stream>>>(tA, tB, tC, 256, 256, 256, -1.f, 15.f);
    bmm_f32<<<dim3(4, 4, 8), 256, 0, stream>>>(tA, tC, tB, 256, 256, 256, -1.f, 13.f);
    bmm_f32<<<dim3(4, 4, 8), 256, 0, stream>>>(zf, tB, zfin, 256, 256, 256, 0.25f, 0.f);

    flash_ml<<<dim3(8, 8, 16), 256, 0, stream>>>(q_l, kT, mlp);
    ml_merge<<<8, 256, 0, stream>>>(mlp, mfin, lfin);
    hipMemsetAsync(kv, 0, (size_t)8 * 256 * 64 * sizeof(float), stream);
    flash_kv<<<dim3(8, 8, 16), 256, 0, stream>>>(q_l, kT, qkv, mfin, lfin, kv);
    bmt_kernel<<<dim3(4, 8), 256, 0, stream>>>(zfin, kv, BmT);
    attn1_out<<<dim3(512, 8), 256, 0, stream>>>(qb, k_lb, BmT, qkv, resk[L], actb);
    transpose_cast<<<dim3(16, 16), 256, 0, stream>>>(outw[L], wT, 512, 512);
    gemm_bf16<2><<<dim3(4, 128), 256, 0, stream>>>(actb, wT, h, outb[L],
                                                   NTOK, 512, 512, NTOK);
  }
  final_head<<<1, 256, 0, stream>>>(h, fnw, fnb, cw, cb, (float*)d_out);
}

// Round 4
// 1575.919 us; speedup vs baseline: 3.2772x; 1.3256x over previous
//
#include <hip/hip_runtime.h>

#define NTOK 16384
#define NDIM 512
#define STP_LD 280   // ushorts per P row in LDS (16B-aligned, bank-friendly)

typedef __attribute__((ext_vector_type(8))) short short8;
typedef __attribute__((ext_vector_type(4))) float f32x4;

__device__ __forceinline__ unsigned short f2bf(float f) {
  unsigned u = __float_as_uint(f);
  u += 0x7fffu + ((u >> 16) & 1u);
  return (unsigned short)(u >> 16);
}

__device__ __forceinline__ void gload_lds16(const void* g, void* l) {
  __builtin_amdgcn_global_load_lds(
      (const __attribute__((address_space(1))) unsigned int*)(unsigned long long)(g),
      (__attribute__((address_space(3))) unsigned int*)(unsigned long long)(l), 16, 0, 0);
}

// ---------------------------------------------------------------------------
// bf16 MFMA GEMM: C(f32)[M][N] = epi(A(bf16)[M][K] @ Bt(bf16)[N][K]^T)
// ---------------------------------------------------------------------------
template<int EPI>
__global__ __launch_bounds__(256) void gemm_bf16(
    const unsigned short* __restrict__ A, const unsigned short* __restrict__ Bt,
    float* __restrict__ C, const float* __restrict__ bias,
    int M, int N, int K, int Mstore)
{
  __shared__ unsigned short As[128 * 32];
  __shared__ unsigned short Bs[128 * 32];
  const int tid = threadIdx.x;
  const int row0 = blockIdx.y * 128, col0 = blockIdx.x * 128;
  const int wave = tid >> 6, lane = tid & 63;
  const int wm = (wave >> 1) * 64, wn = (wave & 1) * 64;
  const int quad = lane >> 4, m16 = lane & 15;

  const int r0 = tid >> 2;
  const int c8 = (tid & 3) * 8;
  const unsigned short* Ag0 = A + (size_t)(row0 + r0) * K + c8;
  const unsigned short* Ag1 = A + (size_t)(row0 + r0 + 64) * K + c8;
  const unsigned short* Bg0 = Bt + (size_t)(col0 + r0) * K + c8;
  const unsigned short* Bg1 = Bt + (size_t)(col0 + r0 + 64) * K + c8;
  char* AsB = (char*)As;
  char* BsB = (char*)Bs;
  const int wb = wave * 1024;

  f32x4 acc[4][4] = {};
  for (int k0 = 0; k0 < K; k0 += 32) {
    gload_lds16(Ag0 + k0, AsB + wb);
    gload_lds16(Ag1 + k0, AsB + 4096 + wb);
    gload_lds16(Bg0 + k0, BsB + wb);
    gload_lds16(Bg1 + k0, BsB + 4096 + wb);
    __syncthreads();
    short8 af[4], bf[4];
#pragma unroll
    for (int i = 0; i < 4; i++) {
      af[i] = *(const short8*)&As[(wm + i * 16 + m16) * 32 + quad * 8];
      bf[i] = *(const short8*)&Bs[(wn + i * 16 + m16) * 32 + quad * 8];
    }
#pragma unroll
    for (int i = 0; i < 4; i++)
#pragma unroll
      for (int j = 0; j < 4; j++)
        acc[i][j] = __builtin_amdgcn_mfma_f32_16x16x32_bf16(af[i], bf[j], acc[i][j], 0, 0, 0);
    __syncthreads();
  }
#pragma unroll
  for (int i = 0; i < 4; i++) {
#pragma unroll
    for (int r = 0; r < 4; r++) {
      int gr = row0 + wm + i * 16 + quad * 4 + r;
      if (gr < Mstore) {
#pragma unroll
        for (int j = 0; j < 4; j++) {
          int gc = col0 + wn + j * 16 + m16;
          float v = acc[i][j][r];
          if (EPI == 1) { v += bias[gc]; v = fmaxf(v, 0.f); }
          if (EPI == 2) { v += bias[gc] + C[(size_t)gr * N + gc]; }
          C[(size_t)gr * N + gc] = v;
        }
      }
    }
  }
}

// ---------------------------------------------------------------------------
// bf16 MFMA batched (8 heads) 256x256x256 GEMM for pinv.
// ---------------------------------------------------------------------------
template<bool WN, bool WT>
__global__ __launch_bounds__(256) void bmm_pinv(
    const unsigned short* __restrict__ A, const unsigned short* __restrict__ Bt,
    unsigned short* __restrict__ Cn, unsigned short* __restrict__ Ct,
    float an, float bn, float at, float bt)
{
  const int hh = blockIdx.z;
  A  += (size_t)hh << 16;
  Bt += (size_t)hh << 16;
  __shared__ unsigned short As[128 * 32];
  __shared__ unsigned short Bs[128 * 32];
  const int tid = threadIdx.x;
  const int row0 = blockIdx.y * 128, col0 = blockIdx.x * 128;
  const int wave = tid >> 6, lane = tid & 63;
  const int wm = (wave >> 1) * 64, wn = (wave & 1) * 64;
  const int quad = lane >> 4, m16 = lane & 15;
  const int r0 = tid >> 2, c8 = (tid & 3) * 8;
  const unsigned short* Ag0 = A + (size_t)(row0 + r0) * 256 + c8;
  const unsigned short* Ag1 = A + (size_t)(row0 + r0 + 64) * 256 + c8;
  const unsigned short* Bg0 = Bt + (size_t)(col0 + r0) * 256 + c8;
  const unsigned short* Bg1 = Bt + (size_t)(col0 + r0 + 64) * 256 + c8;
  char* AsB = (char*)As; char* BsB = (char*)Bs;
  const int wb = wave * 1024;
  f32x4 acc[4][4] = {};
  for (int k0 = 0; k0 < 256; k0 += 32) {
    gload_lds16(Ag0 + k0, AsB + wb);
    gload_lds16(Ag1 + k0, AsB + 4096 + wb);
    gload_lds16(Bg0 + k0, BsB + wb);
    gload_lds16(Bg1 + k0, BsB + 4096 + wb);
    __syncthreads();
    short8 af[4], bf[4];
#pragma unroll
    for (int i = 0; i < 4; i++) {
      af[i] = *(const short8*)&As[(wm + i * 16 + m16) * 32 + quad * 8];
      bf[i] = *(const short8*)&Bs[(wn + i * 16 + m16) * 32 + quad * 8];
    }
#pragma unroll
    for (int i = 0; i < 4; i++)
#pragma unroll
      for (int j = 0; j < 4; j++)
        acc[i][j] = __builtin_amdgcn_mfma_f32_16x16x32_bf16(af[i], bf[j], acc[i][j], 0, 0, 0);
    __syncthreads();
  }
  unsigned short* CnH = Cn + ((size_t)hh << 16);
  unsigned short* CtH = Ct + ((size_t)hh << 16);
#pragma unroll
  for (int i = 0; i < 4; i++) {
#pragma unroll
    for (int r = 0; r < 4; r++) {
      int gr = row0 + wm + i * 16 + quad * 4 + r;
#pragma unroll
      for (int j = 0; j < 4; j++) {
        int gc = col0 + wn + j * 16 + m16;
        float p = acc[i][j][r];
        float diag = (gr == gc) ? 1.f : 0.f;
        if (WN) CnH[(size_t)gr * 256 + gc] = f2bf(an * p + bn * diag);
        if (WT) CtH[(size_t)gc * 256 + gr] = f2bf(at * p + bt * diag);
      }
    }
  }
}

// cast fp32 -> bf16, pad (zero) past nvalid elements
__global__ void castpad_x(const float* __restrict__ x, unsigned short* __restrict__ xb,
                          size_t nvalid) {
  size_t i4 = ((size_t)blockIdx.x * 256 + threadIdx.x) * 4;
  float4 v = make_float4(0.f, 0.f, 0.f, 0.f);
  if (i4 < nvalid) v = *(const float4*)(x + i4);
  ushort4 o;
  o.x = f2bf(v.x); o.y = f2bf(v.y); o.z = f2bf(v.z); o.w = f2bf(v.w);
  *(ushort4*)(xb + i4) = o;
}

// in fp32 [R][C] -> out bf16 [C][R]
__global__ __launch_bounds__(256) void transpose_cast(
    const float* __restrict__ in, unsigned short* __restrict__ out, int R, int C)
{
  __shared__ float tile[32][33];
  int r0 = blockIdx.x * 32, c0 = blockIdx.y * 32;
  int tx = threadIdx.x & 31, ty = threadIdx.x >> 5;
  for (int yy = ty; yy < 32; yy += 8)
    tile[yy][tx] = in[(size_t)(r0 + yy) * C + c0 + tx];
  __syncthreads();
  for (int yy = ty; yy < 32; yy += 8)
    out[(size_t)(c0 + yy) * R + r0 + tx] = f2bf(tile[tx][yy]);
}

// qb = bf16(q * 0.125), q = qkv[:, 0:512]
__global__ void cast_q(const float* __restrict__ qkv, unsigned short* __restrict__ qb) {
  size_t e4 = ((size_t)blockIdx.x * 256 + threadIdx.x) * 4;
  int i = (int)(e4 >> 9), c = (int)(e4 & 511);
  const float* p = qkv + (size_t)i * 1536 + c;
  float4 v = *(const float4*)p;
  ushort4 o;
  o.x = f2bf(v.x * 0.125f); o.y = f2bf(v.y * 0.125f);
  o.z = f2bf(v.z * 0.125f); o.w = f2bf(v.w * 0.125f);
  *(ushort4*)(qb + e4) = o;
}

// kb = bf16(qkv[:, 512:1024])  [16384][512]
__global__ void cast_k(const float* __restrict__ qkv, unsigned short* __restrict__ kb) {
  size_t e4 = ((size_t)blockIdx.x * 256 + threadIdx.x) * 4;
  int i = (int)(e4 >> 9), c = (int)(e4 & 511);
  const float* p = qkv + (size_t)i * 1536 + 512 + c;
  float4 v = *(const float4*)p;
  ushort4 o;
  o.x = f2bf(v.x); o.y = f2bf(v.y); o.z = f2bf(v.z); o.w = f2bf(v.w);
  *(ushort4*)(kb + e4) = o;
}

// vTb[c][i] = bf16(qkv[i][1024 + c])   [512][16384]
__global__ __launch_bounds__(256) void transpose_cast_v(
    const float* __restrict__ qkv, unsigned short* __restrict__ vTb)
{
  __shared__ float tile[32][33];
  int i0 = blockIdx.x * 32, c0 = blockIdx.y * 32;
  int tx = threadIdx.x & 31, ty = threadIdx.x >> 5;
  for (int yy = ty; yy < 32; yy += 8)
    tile[yy][tx] = qkv[(size_t)(i0 + yy) * 1536 + 1024 + c0 + tx];
  __syncthreads();
  for (int yy = ty; yy < 32; yy += 8)
    vTb[(size_t)(c0 + yy) * NTOK + i0 + tx] = f2bf(tile[tx][yy]);
}

__global__ void cast_bf2f(const unsigned short* __restrict__ in, float* __restrict__ out) {
  int i = blockIdx.x * 256 + threadIdx.x;
  out[i] = __uint_as_float((unsigned)in[i] << 16);
}

// ---------------------------------------------------------------------------
// fp32 batched GEMM (pinv polish): C = alpha*(A@B) + beta*I
// ---------------------------------------------------------------------------
__global__ __launch_bounds__(256) void bmm_f32(
    const float* __restrict__ A, const float* __restrict__ B, float* __restrict__ C,
    int M, int N, int K, float alpha, float beta)
{
  const int h = blockIdx.z;
  A += (size_t)h * M * K; B += (size_t)h * K * N; C += (size_t)h * M * N;
  __shared__ float As[16][64];
  __shared__ float Bs[16][64];
  const int tid = threadIdx.x;
  const int row0 = blockIdx.y * 64, col0 = blockIdx.x * 64;
  const int ty = tid >> 4, tx = tid & 15;
  const int ar = tid >> 2, ac = (tid & 3) << 2;
  const int bk = tid >> 4, bj = (tid & 15) << 2;
  float acc[4][4] = {};
  for (int k0 = 0; k0 < K; k0 += 16) {
    float4 a = *(const float4*)(A + (size_t)(row0 + ar) * K + k0 + ac);
    As[ac + 0][ar] = a.x; As[ac + 1][ar] = a.y; As[ac + 2][ar] = a.z; As[ac + 3][ar] = a.w;
    *(float4*)&Bs[bk][bj] = *(const float4*)(B + (size_t)(k0 + bk) * N + col0 + bj);
    __syncthreads();
#pragma unroll
    for (int kk = 0; kk < 16; kk++) {
      float4 av = *(float4*)&As[kk][ty << 2];
      float4 bv = *(float4*)&Bs[kk][tx << 2];
      float a4[4] = {av.x, av.y, av.z, av.w};
      float b4[4] = {bv.x, bv.y, bv.z, bv.w};
#pragma unroll
      for (int ii = 0; ii < 4; ii++)
#pragma unroll
        for (int jj = 0; jj < 4; jj++) acc[ii][jj] += a4[ii] * b4[jj];
    }
    __syncthreads();
  }
#pragma unroll
  for (int ii = 0; ii < 4; ii++) {
    int gr = row0 + (ty << 2) + ii;
#pragma unroll
    for (int jj = 0; jj < 4; jj++) {
      int gc = col0 + (tx << 2) + jj;
      float v = alpha * acc[ii][jj];
      if (gr == gc) v += beta;
      C[(size_t)gr * N + gc] = v;
    }
  }
}

__global__ void eyesub(const float* __restrict__ in, float* __restrict__ out, float c) {
  int idx = blockIdx.x * 256 + threadIdx.x;
  int i = (idx >> 8) & 255, j = idx & 255;
  out[idx] = ((i == j) ? c : 0.f) - in[idx];
}

__global__ void cls_copy(const float* __restrict__ cls, float* __restrict__ h) {
  int t = threadIdx.x;
  if (t < 512) h[t] = cls[t];
}

// per-row layernorm over 512, writes bf16
__global__ __launch_bounds__(256) void layernorm_rows(
    const float* __restrict__ x, unsigned short* __restrict__ y,
    const float* __restrict__ w, const float* __restrict__ b)
{
  const int row = blockIdx.x, tid = threadIdx.x;
  const float* xr = x + (size_t)row * NDIM;
  float2 v = ((const float2*)xr)[tid];
  float sum = v.x + v.y, sq = v.x * v.x + v.y * v.y;
#pragma unroll
  for (int off = 32; off; off >>= 1) { sum += __shfl_xor(sum, off); sq += __shfl_xor(sq, off); }
  __shared__ float r1[4], r2[4];
  if ((tid & 63) == 0) { r1[tid >> 6] = sum; r2[tid >> 6] = sq; }
  __syncthreads();
  sum = r1[0] + r1[1] + r1[2] + r1[3];
  sq  = r2[0] + r2[1] + r2[2] + r2[3];
  float mu = sum * (1.f / 512.f);
  float var = sq * (1.f / 512.f) - mu * mu;
  float rs = rsqrtf(var + 1e-5f);
  float a = (v.x - mu) * rs * w[2 * tid]     + b[2 * tid];
  float c = (v.y - mu) * rs * w[2 * tid + 1] + b[2 * tid + 1];
  ((unsigned*)(y + (size_t)row * NDIM))[tid] = (unsigned)f2bf(a) | ((unsigned)f2bf(c) << 16);
}

// landmark pooling (q scaled by 1/8); fp32 + bf16 outputs
__global__ void pool_lm(const float* __restrict__ qkv,
                        float* __restrict__ q_l, float* __restrict__ k_l,
                        unsigned short* __restrict__ k_lb, unsigned short* __restrict__ q_lb)
{
  int idx = blockIdx.x * 256 + threadIdx.x;          // (h,j,d) 8*256*64
  int d = idx & 63, j = (idx >> 6) & 255, h = idx >> 14;
  const float* bq = qkv + (size_t)(j << 6) * 1536 + (h << 6) + d;
  float sq = 0.f, sk = 0.f;
  for (int u = 0; u < 64; u++) { sq += bq[(size_t)u * 1536]; sk += bq[(size_t)u * 1536 + 512]; }
  float kl = sk * (1.f / 64.f);
  float ql = sq * (1.f / 64.f) * 0.125f;
  q_l[idx] = ql;
  k_l[idx] = kl;
  k_lb[idx] = f2bf(kl);
  q_lb[idx] = f2bf(ql);
}

// attn2 = softmax(q_l @ k_l^T) rows; fp32 + bf16 outputs
__global__ __launch_bounds__(256) void attn2_softmax(
    const float* __restrict__ q_l, const float* __restrict__ k_l,
    float* __restrict__ x2, unsigned short* __restrict__ x2b)
{
  int row = blockIdx.x, h = blockIdx.y, j = threadIdx.x;
  __shared__ float qrow[64];
  __shared__ float red[4];
  if (j < 64) qrow[j] = q_l[(size_t)(h * 256 + row) * 64 + j];
  __syncthreads();
  const float* kr = k_l + (size_t)(h * 256 + j) * 64;
  float s = 0.f;
#pragma unroll 8
  for (int d = 0; d < 64; d++) s += qrow[d] * kr[d];
  float m = s;
#pragma unroll
  for (int off = 32; off; off >>= 1) m = fmaxf(m, __shfl_xor(m, off));
  if ((j & 63) == 0) red[j >> 6] = m;
  __syncthreads();
  m = fmaxf(fmaxf(red[0], red[1]), fmaxf(red[2], red[3]));
  __syncthreads();
  float e = __expf(s - m), l = e;
#pragma unroll
  for (int off = 32; off; off >>= 1) l += __shfl_xor(l, off);
  if ((j & 63) == 0) red[j >> 6] = l;
  __syncthreads();
  l = red[0] + red[1] + red[2] + red[3];
  float val = e / l;
  size_t o = ((size_t)(h * 256 + row) << 8) + j;
  x2[o] = val;
  x2b[o] = f2bf(val);
}

__global__ __launch_bounds__(256) void colrow_max(const float* __restrict__ x2,
                                                  float* __restrict__ scal)
{
  int t = threadIdx.x, r = blockIdx.x, h = blockIdx.y;
  float rv = x2[((size_t)(h * 256 + r) << 8) + t];
  float cv = x2[((size_t)(h * 256 + t) << 8) + r];
#pragma unroll
  for (int off = 32; off; off >>= 1) { rv += __shfl_xor(rv, off); cv += __shfl_xor(cv, off); }
  __shared__ float rr[4], cc[4];
  if ((t & 63) == 0) { rr[t >> 6] = rv; cc[t >> 6] = cv; }
  __syncthreads();
  if (t == 0) {
    float rs = rr[0] + rr[1] + rr[2] + rr[3];
    float cs = cc[0] + cc[1] + cc[2] + cc[3];
    atomicMax((unsigned int*)&scal[0], __float_as_uint(rs));
    atomicMax((unsigned int*)&scal[1], __float_as_uint(cs));
  }
}

// z0 (bf16, [j][i]) and z0^T (bf16, [i][j]) from x2
__global__ void zinit_bf(const float* __restrict__ x2, unsigned short* __restrict__ zb,
                         unsigned short* __restrict__ zTb, const float* __restrict__ scal)
{
  int idx = blockIdx.x * 256 + threadIdx.x;
  int hh = idx >> 16, i = (idx >> 8) & 255, j = idx & 255;
  float den = scal[0] * scal[1];
  float val = x2[idx] / den;
  unsigned short b = f2bf(val);
  zTb[idx] = b;
  zb[(hh << 16) + (j << 8) + i] = b;
}

// ---------------------------------------------------------------------------
// single-pass MFMA flash attn3@v with key-split partials.
// grid (32 ks, 4 qg, 8 h), block 256 (4 independent waves, 16 qrows each)
// Opart[ks][h][256][64] f32, mlpart[ks][h][256][2] f32
// ---------------------------------------------------------------------------
__global__ __launch_bounds__(256) void flash_fused(
    const unsigned short* __restrict__ q_lb, const unsigned short* __restrict__ kb,
    const unsigned short* __restrict__ vTb,
    float* __restrict__ Opart, float* __restrict__ mlpart)
{
  const int ks = blockIdx.x, qg = blockIdx.y, h = blockIdx.z;
  const int tid = threadIdx.x;
  const int wave = tid >> 6, lane = tid & 63;
  const int quad = lane >> 4, m16 = lane & 15;
  __shared__ unsigned short pbuf_all[4][16 * 72];
  unsigned short* pbuf = pbuf_all[wave];

  const int qrow_w = qg * 64 + wave * 16;
  const unsigned short* qbase = q_lb + ((size_t)h << 14) + (size_t)(qrow_w + m16) * 64;
  short8 aq0 = *(const short8*)(qbase + quad * 8);
  short8 aq1 = *(const short8*)(qbase + 32 + quad * 8);

  float m_e[4], l_e[4];
#pragma unroll
  for (int e = 0; e < 4; e++) { m_e[e] = -1e30f; l_e[e] = 0.f; }
  f32x4 acc_o[4] = {};

  const int key00 = ks * 512;
  for (int c = 0; c < 8; c++) {
    const int key0 = key00 + c * 64;
    // S = q_l @ k^T (16 qrows x 64 keys)
    f32x4 s[4] = {};
#pragma unroll
    for (int kt = 0; kt < 4; kt++) {
      const unsigned short* kr = kb + (size_t)(key0 + kt * 16 + m16) * 512 + (h << 6);
      short8 b0 = *(const short8*)(kr + quad * 8);
      short8 b1 = *(const short8*)(kr + 32 + quad * 8);
      s[kt] = __builtin_amdgcn_mfma_f32_16x16x32_bf16(aq0, b0, s[kt], 0, 0, 0);
      s[kt] = __builtin_amdgcn_mfma_f32_16x16x32_bf16(aq1, b1, s[kt], 0, 0, 0);
    }
    // online softmax per row (row = quad*4+e, cols spread over m16 x kt)
#pragma unroll
    for (int e = 0; e < 4; e++) {
      float mx = fmaxf(fmaxf(s[0][e], s[1][e]), fmaxf(s[2][e], s[3][e]));
      mx = fmaxf(mx, __shfl_xor(mx, 1));
      mx = fmaxf(mx, __shfl_xor(mx, 2));
      mx = fmaxf(mx, __shfl_xor(mx, 4));
      mx = fmaxf(mx, __shfl_xor(mx, 8));
      float mn = fmaxf(m_e[e], mx);
      float scale = __expf(m_e[e] - mn);
      m_e[e] = mn;
      float sum = 0.f;
#pragma unroll
      for (int kt = 0; kt < 4; kt++) {
        float ev = __expf(s[kt][e] - mn);
        s[kt][e] = ev;
        sum += ev;
      }
      sum += __shfl_xor(sum, 1); sum += __shfl_xor(sum, 2);
      sum += __shfl_xor(sum, 4); sum += __shfl_xor(sum, 8);
      l_e[e] = l_e[e] * scale + sum;
#pragma unroll
      for (int dt = 0; dt < 4; dt++) acc_o[dt][e] *= scale;
    }
    // P -> per-wave LDS (C-frag -> A-frag transpose)
#pragma unroll
    for (int kt = 0; kt < 4; kt++)
#pragma unroll
      for (int e = 0; e < 4; e++)
        pbuf[(quad * 4 + e) * 72 + kt * 16 + m16] = f2bf(s[kt][e]);
    asm volatile("s_waitcnt lgkmcnt(0)" ::: "memory");
    short8 ap0 = *(const short8*)&pbuf[m16 * 72 + quad * 8];
    short8 ap1 = *(const short8*)&pbuf[m16 * 72 + 32 + quad * 8];
    // O += P @ V  (B-operand from vTb rows = d)
#pragma unroll
    for (int dt = 0; dt < 4; dt++) {
      const unsigned short* vr = vTb + (size_t)((h << 6) + dt * 16 + m16) * NTOK + key0;
      short8 bv0 = *(const short8*)(vr + quad * 8);
      short8 bv1 = *(const short8*)(vr + 32 + quad * 8);
      acc_o[dt] = __builtin_amdgcn_mfma_f32_16x16x32_bf16(ap0, bv0, acc_o[dt], 0, 0, 0);
      acc_o[dt] = __builtin_amdgcn_mfma_f32_16x16x32_bf16(ap1, bv1, acc_o[dt], 0, 0, 0);
    }
  }
  float* ob = Opart + ((size_t)(ks * 8 + h) * 256 + qrow_w) * 64;
#pragma unroll
  for (int dt = 0; dt < 4; dt++)
#pragma unroll
    for (int e = 0; e < 4; e++)
      ob[(size_t)(quad * 4 + e) * 64 + dt * 16 + m16] = acc_o[dt][e];
  if (m16 == 0) {
    float* mlb = mlpart + ((size_t)(ks * 8 + h) * 256 + qrow_w) * 2;
#pragma unroll
    for (int e = 0; e < 4; e++) {
      mlb[(quad * 4 + e) * 2]     = m_e[e];
      mlb[(quad * 4 + e) * 2 + 1] = l_e[e];
    }
  }
}

// combine key-split partials -> kv[h][256][64]; grid (8 rc, 8 h), block 256
__global__ __launch_bounds__(256) void flash_merge(
    const float* __restrict__ Opart, const float* __restrict__ mlpart,
    float* __restrict__ kv)
{
  const int rc = blockIdx.x, h = blockIdx.y, tid = threadIdx.x;
  const int r = rc * 32 + (tid >> 3);
  const int d0 = (tid & 7) * 8;
  float M = -1e30f;
  for (int ks = 0; ks < 32; ks++)
    M = fmaxf(M, mlpart[((size_t)(ks * 8 + h) * 256 + r) * 2]);
  float L = 0.f;
  float o[8];
#pragma unroll
  for (int j = 0; j < 8; j++) o[j] = 0.f;
  for (int ks = 0; ks < 32; ks++) {
    const float* mlb = mlpart + ((size_t)(ks * 8 + h) * 256 + r) * 2;
    float w = __expf(mlb[0] - M);
    L += mlb[1] * w;
    const float* op = Opart + ((size_t)(ks * 8 + h) * 256 + r) * 64 + d0;
    float4 a = *(const float4*)op;
    float4 b = *(const float4*)(op + 4);
    o[0] += a.x * w; o[1] += a.y * w; o[2] += a.z * w; o[3] += a.w * w;
    o[4] += b.x * w; o[5] += b.y * w; o[6] += b.z * w; o[7] += b.w * w;
  }
  float invL = 1.f / L;
  float* out = kv + ((size_t)(h * 256 + r)) * 64 + d0;
#pragma unroll
  for (int j = 0; j < 8; j++) out[j] = o[j] * invL;
}

// BmT[h][d][j] = sum_k zf[h][j][k] * kv[h][k][d]  (bf16 out)
__global__ __launch_bounds__(256) void bmt_kernel(
    const float* __restrict__ zf, const float* __restrict__ kv,
    unsigned short* __restrict__ BmT)
{
  const int jb = blockIdx.x, hh = blockIdx.y, tid = threadIdx.x;
  __shared__ float zt[64 * 256];
  const float* zsrc = zf + ((size_t)hh << 16) + (size_t)(jb * 64) * 256;
  for (int rep = 0; rep < 16; rep++) {
    int e4 = (rep * 256 + tid) * 4;
    *(float4*)&zt[e4] = *(const float4*)(zsrc + e4);
  }
  __syncthreads();
  const int d = tid & 63, jg = tid >> 6;
  const float* kvh = kv + ((size_t)hh << 14) + d;
  float acc[16];
#pragma unroll
  for (int u = 0; u < 16; u++) acc[u] = 0.f;
  for (int k0 = 0; k0 < 256; k0 += 8) {
    float kv8[8];
#pragma unroll
    for (int u = 0; u < 8; u++) kv8[u] = kvh[(size_t)(k0 + u) << 6];
#pragma unroll
    for (int jj = 0; jj < 16; jj++) {
      const float* zr = &zt[(jg * 16 + jj) * 256 + k0];
#pragma unroll
      for (int u = 0; u < 8; u++) acc[jj] += zr[u] * kv8[u];
    }
  }
  unsigned short* ob = BmT + ((size_t)hh << 14) + (size_t)d * 256 + jb * 64 + jg * 16;
#pragma unroll
  for (int jj = 0; jj < 16; jj++) ob[jj] = f2bf(acc[jj]);
}

// ---------------------------------------------------------------------------
// fused attn1: softmax(q@k_l^T) @ Bm + depthwise-conv(v) -> attn_out bf16
// ---------------------------------------------------------------------------
__global__ __launch_bounds__(256) void attn1_out(
    const unsigned short* __restrict__ qb, const unsigned short* __restrict__ k_lb,
    const unsigned short* __restrict__ BmT, const float* __restrict__ qkv,
    const float* __restrict__ res_k, unsigned short* __restrict__ attn_out)
{
  const int qc = blockIdx.x, h = blockIdx.y, tid = threadIdx.x;
  const int q0 = qc * 32;
  const int wave = tid >> 6, lane = tid & 63;
  const int quad = lane >> 4, m16 = lane & 15;

  __shared__ unsigned short stp[32 * STP_LD];
  __shared__ float v_lds[64 * 68];
  __shared__ float redm[4][32], redl[4][32];
  __shared__ float rk[33];

  if (tid < 33) rk[tid] = res_k[h * 33 + tid];

  {
    int vr = tid >> 2, seg = tid & 3;
    int gi = q0 - 16 + vr;
    const float* vp = qkv + (size_t)gi * 1536 + 1024 + (h << 6) + seg * 16;
    bool ok = (gi >= 0 && gi < NTOK);
#pragma unroll
    for (int u = 0; u < 4; u++) {
      float4 vv = ok ? *(const float4*)(vp + 4 * u) : make_float4(0.f, 0.f, 0.f, 0.f);
      *(float4*)&v_lds[vr * 68 + seg * 16 + 4 * u] = vv;
    }
  }

  f32x4 acc1[2][4] = {};
  {
    const unsigned short* qbase = qb + (size_t)q0 * 512 + (h << 6);
    const unsigned short* kbase = k_lb + ((size_t)h << 14) + (size_t)(wave * 64) * 64;
#pragma unroll
    for (int kc = 0; kc < 2; kc++) {
      short8 aq[2], bk[4];
#pragma unroll
      for (int i = 0; i < 2; i++)
        aq[i] = *(const short8*)(qbase + (size_t)(i * 16 + m16) * 512 + kc * 32 + quad * 8);
#pragma unroll
      for (int n = 0; n < 4; n++)
        bk[n] = *(const short8*)(kbase + (size_t)(n * 16 + m16) * 64 + kc * 32 + quad * 8);
#pragma unroll
      for (int i = 0; i < 2; i++)
#pragma unroll
        for (int n = 0; n < 4; n++)
          acc1[i][n] = __builtin_amdgcn_mfma_f32_16x16x32_bf16(aq[i], bk[n], acc1[i][n], 0, 0, 0);
    }
  }
#pragma unroll
  for (int i = 0; i < 2; i++) {
#pragma unroll
    for (int e = 0; e < 4; e++) {
      float mx = fmaxf(fmaxf(acc1[i][0][e], acc1[i][1][e]), fmaxf(acc1[i][2][e], acc1[i][3][e]));
      mx = fmaxf(mx, __shfl_xor(mx, 1));
      mx = fmaxf(mx, __shfl_xor(mx, 2));
      mx = fmaxf(mx, __shfl_xor(mx, 4));
      mx = fmaxf(mx, __shfl_xor(mx, 8));
      if (m16 == 0) redm[wave][i * 16 + quad * 4 + e] = mx;
    }
  }
  __syncthreads();
#pragma unroll
  for (int i = 0; i < 2; i++) {
#pragma unroll
    for (int e = 0; e < 4; e++) {
      int r = i * 16 + quad * 4 + e;
      float gm = fmaxf(fmaxf(redm[0][r], redm[1][r]), fmaxf(redm[2][r], redm[3][r]));
      float s = 0.f;
#pragma unroll
      for (int n = 0; n < 4; n++) {
        float ev = __expf(acc1[i][n][e] - gm);
        acc1[i][n][e] = ev;
        s += ev;
      }
      s += __shfl_xor(s, 1); s += __shfl_xor(s, 2);
      s += __shfl_xor(s, 4); s += __shfl_xor(s, 8);
      if (m16 == 0) redl[wave][r] = s;
    }
  }
#pragma unroll
  for (int i = 0; i < 2; i++)
#pragma unroll
    for (int n = 0; n < 4; n++) {
      int col = wave * 64 + n * 16 + m16;
#pragma unroll
      for (int e = 0; e < 4; e++)
        stp[(i * 16 + quad * 4 + e) * STP_LD + col] = f2bf(acc1[i][n][e]);
    }
  __syncthreads();

  const int mi3 = (wave & 1) * 16;
  const int nbase = (wave >> 1) * 32;
  f32x4 acc3[2] = {};
  {
    const unsigned short* bbase = BmT + ((size_t)h << 14);
#pragma unroll
    for (int kc = 0; kc < 8; kc++) {
      short8 ap = *(const short8*)&stp[(mi3 + m16) * STP_LD + kc * 32 + quad * 8];
#pragma unroll
      for (int t = 0; t < 2; t++) {
        short8 bp = *(const short8*)(bbase + (size_t)(nbase + t * 16 + m16) * 256 + kc * 32 + quad * 8);
        acc3[t] = __builtin_amdgcn_mfma_f32_16x16x32_bf16(ap, bp, acc3[t], 0, 0, 0);
      }
    }
  }
#pragma unroll
  for (int t = 0; t < 2; t++) {
    int d = nbase + t * 16 + m16;
#pragma unroll
    for (int e = 0; e < 4; e++) {
      int lr = mi3 + quad * 4 + e;
      float l = redl[0][lr] + redl[1][lr] + redl[2][lr] + redl[3][lr];
      float v = acc3[t][e] / l;
      float cv = 0.f;
#pragma unroll
      for (int u = 0; u < 33; u++) cv += rk[u] * v_lds[(lr + u) * 68 + d];
      int gi = q0 + lr;
      attn_out[((size_t)gi << 9) + (h << 6) + d] = f2bf(v + cv);
    }
  }
}

// final: layernorm row0 -> 4 logits -> sigmoid + cumprod
__global__ __launch_bounds__(256) void final_head(
    const float* __restrict__ hrow, const float* __restrict__ nw, const float* __restrict__ nb,
    const float* __restrict__ cw, const float* __restrict__ cb, float* __restrict__ out)
{
  const int tid = threadIdx.x;
  __shared__ float ln0[512];
  __shared__ float r1[4], r2[4];
  __shared__ float lg[4][4];
  float2 v = ((const float2*)hrow)[tid];
  float sum = v.x + v.y, sq = v.x * v.x + v.y * v.y;
#pragma unroll
  for (int off = 32; off; off >>= 1) { sum += __shfl_xor(sum, off); sq += __shfl_xor(sq, off); }
  if ((tid & 63) == 0) { r1[tid >> 6] = sum; r2[tid >> 6] = sq; }
  __syncthreads();
  sum = r1[0] + r1[1] + r1[2] + r1[3];
  sq  = r2[0] + r2[1] + r2[2] + r2[3];
  float mu = sum * (1.f / 512.f);
  float var = sq * (1.f / 512.f) - mu * mu;
  float rs = rsqrtf(var + 1e-5f);
  ln0[2 * tid]     = (v.x - mu) * rs * nw[2 * tid]     + nb[2 * tid];
  ln0[2 * tid + 1] = (v.y - mu) * rs * nw[2 * tid + 1] + nb[2 * tid + 1];
  __syncthreads();
  float p[4] = {0.f, 0.f, 0.f, 0.f};
  for (int k = tid; k < 512; k += 256) {
    float lv = ln0[k];
#pragma unroll
    for (int c = 0; c < 4; c++) p[c] += lv * cw[k * 4 + c];
  }
#pragma unroll
  for (int off = 32; off; off >>= 1)
#pragma unroll
    for (int c = 0; c < 4; c++) p[c] += __shfl_xor(p[c], off);
  if ((tid & 63) == 0) {
    int w = tid >> 6;
#pragma unroll
    for (int c = 0; c < 4; c++) lg[w][c] = p[c];
  }
  __syncthreads();
  if (tid == 0) {
    float cum = 1.f;
    for (int c = 0; c < 4; c++) {
      float logit = lg[0][c] + lg[1][c] + lg[2][c] + lg[3][c] + cb[c];
      float hz = 1.f / (1.f + __expf(-logit));
      out[c] = hz;
      cum *= (1.f - hz);
      out[4 + c] = cum;
    }
  }
}

// ---------------------------------------------------------------------------
extern "C" void kernel_launch(void* const* d_in, const int* in_sizes, int n_in,
                              void* d_out, int out_size, void* d_ws, size_t ws_size,
                              hipStream_t stream)
{
  (void)in_sizes; (void)n_in; (void)out_size; (void)ws_size;
  const float* x    = (const float*)d_in[0];
  const float* fc_w = (const float*)d_in[1];
  const float* fc_b = (const float*)d_in[2];
  const float* cls  = (const float*)d_in[3];
  const float* nw[2]   = {(const float*)d_in[4],  (const float*)d_in[10]};
  const float* nb[2]   = {(const float*)d_in[5],  (const float*)d_in[11]};
  const float* qkvw[2] = {(const float*)d_in[6],  (const float*)d_in[12]};
  const float* outw[2] = {(const float*)d_in[7],  (const float*)d_in[13]};
  const float* outb[2] = {(const float*)d_in[8],  (const float*)d_in[14]};
  const float* resk[2] = {(const float*)d_in[9],  (const float*)d_in[15]};
  const float* fnw = (const float*)d_in[16];
  const float* fnb = (const float*)d_in[17];
  const float* cw  = (const float*)d_in[18];
  const float* cb  = (const float*)d_in[19];

  float* ws = (float*)d_ws;
  float* h    = ws; ws += (size_t)NTOK * NDIM;
  float* qkv  = ws; ws += (size_t)NTOK * 1536;   // aliased as xb (bf16) pre-loop
  float* big  = ws; ws += (size_t)NTOK * NDIM;   // Opart + mlpart (old kT slot)
  float* q_l  = ws; ws += 8 * 256 * 64;
  float* k_l  = ws; ws += 8 * 256 * 64;
  float* x2   = ws; ws += 8 * 256 * 256;
  float* zf   = ws; ws += 8 * 256 * 256;
  float* zfin = ws; ws += 8 * 256 * 256;
  float* tA   = ws; ws += 8 * 256 * 256;
  float* tB   = ws; ws += 8 * 256 * 256;
  float* tC   = ws; ws += 8 * 256 * 256;
  float* kv   = ws; ws += 8 * 256 * 64;
  float* scal = ws; ws += 64;
  unsigned short* actb = (unsigned short*)ws; ws += (size_t)NTOK * NDIM / 2;  // also kb
  unsigned short* wT   = (unsigned short*)ws; ws += (1536 * 512) / 2;
  unsigned short* qb   = (unsigned short*)ws; ws += (size_t)NTOK * NDIM / 2;  // also vTb
  unsigned short* k_lb = (unsigned short*)ws; ws += (8 * 256 * 64) / 2;
  unsigned short* q_lb = (unsigned short*)ws; ws += (8 * 256 * 64) / 2;
  unsigned short* x2b  = (unsigned short*)ws; ws += (8 * 256 * 256) / 2;
  unsigned short* zb0  = (unsigned short*)ws; ws += (8 * 256 * 256) / 2;
  unsigned short* zb1  = (unsigned short*)ws; ws += (8 * 256 * 256) / 2;
  unsigned short* zT0  = (unsigned short*)ws; ws += (8 * 256 * 256) / 2;
  unsigned short* zT1  = (unsigned short*)ws; ws += (8 * 256 * 256) / 2;
  unsigned short* xzb  = (unsigned short*)ws; ws += (8 * 256 * 256) / 2;
  unsigned short* t1T  = (unsigned short*)ws; ws += (8 * 256 * 256) / 2;
  unsigned short* t2T  = (unsigned short*)ws; ws += (8 * 256 * 256) / 2;
  unsigned short* t3T  = (unsigned short*)ws; ws += (8 * 256 * 256) / 2;
  unsigned short* BmT  = (unsigned short*)ws; ws += (8 * 64 * 256) / 2;
  unsigned short* xb = (unsigned short*)qkv;   // bf16 padded x, dead before qkv use
  unsigned short* kb  = actb;                  // alias: dead between qkv-gemm and attn1_out
  unsigned short* vTb = qb;                    // alias: dead before cast_q
  float* Opart  = big;                          // 32*8*256*64 f32
  float* mlpart = big + (size_t)32 * 8 * 256 * 64;

  unsigned short* zbp[2] = {zb0, zb1};
  unsigned short* zTp[2] = {zT0, zT1};

  // ---- fc + relu ----
  castpad_x<<<16384, 256, 0, stream>>>(x, xb, (size_t)16383 * 1024);
  transpose_cast<<<dim3(32, 16), 256, 0, stream>>>(fc_w, wT, 1024, 512);
  gemm_bf16<1><<<dim3(4, 128), 256, 0, stream>>>(xb, wT, h + 512, fc_b,
                                                 16384, 512, 1024, 16383);
  cls_copy<<<1, 512, 0, stream>>>(cls, h);

  for (int L = 0; L < 2; L++) {
    layernorm_rows<<<NTOK, 256, 0, stream>>>(h, actb, nw[L], nb[L]);
    transpose_cast<<<dim3(16, 48), 256, 0, stream>>>(qkvw[L], wT, 512, 1536);
    gemm_bf16<0><<<dim3(12, 128), 256, 0, stream>>>(actb, wT, qkv, nullptr,
                                                    NTOK, 1536, 512, NTOK);
    cast_k<<<8192, 256, 0, stream>>>(qkv, kb);                  // kb over dead actb
    transpose_cast_v<<<dim3(512, 16), 256, 0, stream>>>(qkv, vTb);  // vTb over qb slot
    pool_lm<<<512, 256, 0, stream>>>(qkv, q_l, k_l, k_lb, q_lb);
    attn2_softmax<<<dim3(256, 8), 256, 0, stream>>>(q_l, k_l, x2, x2b);
    hipMemsetAsync(scal, 0, 2 * sizeof(float), stream);
    colrow_max<<<dim3(256, 8), 256, 0, stream>>>(x2, scal);
    zinit_bf<<<2048, 256, 0, stream>>>(x2, zbp[0], zTp[0], scal);

    // 5 bf16 Newton iterations + fp32 polish
    int cur = 0;
    dim3 pg(2, 2, 8);
    for (int it = 0; it < 5; it++) {
      bmm_pinv<true,  true><<<pg, 256, 0, stream>>>(x2b, zTp[cur], xzb, t1T, 1.f, 0.f, -1.f, 7.f);
      bmm_pinv<false, true><<<pg, 256, 0, stream>>>(xzb, t1T, xzb, t2T, 0.f, 0.f, -1.f, 15.f);
      bmm_pinv<false, true><<<pg, 256, 0, stream>>>(xzb, t2T, xzb, t3T, 0.f, 0.f, -1.f, 13.f);
      bmm_pinv<true,  true><<<pg, 256, 0, stream>>>(zbp[cur], t3T, zbp[cur ^ 1], zTp[cur ^ 1],
                                                    0.25f, 0.f, 0.25f, 0.f);
      cur ^= 1;
    }
    cast_bf2f<<<2048, 256, 0, stream>>>(zbp[cur], zf);
    bmm_f32<<<dim3(4, 4, 8), 256, 0, stream>>>(x2, zf, tA, 256, 256, 256, 1.f, 0.f);
    eyesub<<<2048, 256, 0, stream>>>(tA, tB, 7.f);
    bmm_f32<<<dim3(4, 4, 8), 256, 0, stream>>>(tA, tB, tC, 256, 256, 256, -1.f, 15.f);
    bmm_f32<<<dim3(4, 4, 8), 256, 0, stream>>>(tA, tC, tB, 256, 256, 256, -1.f, 13.f);
    bmm_f32<<<dim3(4, 4, 8), 256, 0, stream>>>(zf, tB, zfin, 256, 256, 256, 0.25f, 0.f);

    // single-pass MFMA flash attn3@v
    flash_fused<<<dim3(32, 4, 8), 256, 0, stream>>>(q_lb, kb, vTb, Opart, mlpart);
    flash_merge<<<dim3(8, 8), 256, 0, stream>>>(Opart, mlpart, kv);
    bmt_kernel<<<dim3(4, 8), 256, 0, stream>>>(zfin, kv, BmT);
    cast_q<<<8192, 256, 0, stream>>>(qkv, qb);                  // qb over dead vTb
    attn1_out<<<dim3(512, 8), 256, 0, stream>>>(qb, k_lb, BmT, qkv, resk[L], actb);
    transpose_cast<<<dim3(16, 16), 256, 0, stream>>>(outw[L], wT, 512, 512);
    gemm_bf16<2><<<dim3(4, 128), 256, 0, stream>>>(actb, wT, h, outb[L],
                                                   NTOK, 512, 512, NTOK);
  }
  final_head<<<1, 256, 0, stream>>>(h, fnw, fnb, cw, cb, (float*)d_out);
}

// Round 5
// 1468.732 us; speedup vs baseline: 3.5164x; 1.0730x over previous
//
#include <hip/hip_runtime.h>

#define NTOK 16384
#define NDIM 512
#define STP_LD 280   // ushorts per P row in LDS (16B-aligned, bank-friendly)

typedef __attribute__((ext_vector_type(8))) short short8;
typedef __attribute__((ext_vector_type(4))) float f32x4;

__device__ __forceinline__ unsigned short f2bf(float f) {
  unsigned u = __float_as_uint(f);
  u += 0x7fffu + ((u >> 16) & 1u);
  return (unsigned short)(u >> 16);
}
__device__ __forceinline__ float bf2f(unsigned short u) {
  return __uint_as_float((unsigned)u << 16);
}

__device__ __forceinline__ void gload_lds16(const void* g, void* l) {
  __builtin_amdgcn_global_load_lds(
      (const __attribute__((address_space(1))) unsigned int*)(unsigned long long)(g),
      (__attribute__((address_space(3))) unsigned int*)(unsigned long long)(l), 16, 0, 0);
}

// ---------------------------------------------------------------------------
// bf16 MFMA GEMM: C(f32)[M][N] = epi(A(bf16)[M][K] @ Bt(bf16)[N][K]^T)
// ---------------------------------------------------------------------------
template<int EPI>
__global__ __launch_bounds__(256) void gemm_bf16(
    const unsigned short* __restrict__ A, const unsigned short* __restrict__ Bt,
    float* __restrict__ C, const float* __restrict__ bias,
    int M, int N, int K, int Mstore)
{
  __shared__ unsigned short As[128 * 32];
  __shared__ unsigned short Bs[128 * 32];
  const int tid = threadIdx.x;
  const int row0 = blockIdx.y * 128, col0 = blockIdx.x * 128;
  const int wave = tid >> 6, lane = tid & 63;
  const int wm = (wave >> 1) * 64, wn = (wave & 1) * 64;
  const int quad = lane >> 4, m16 = lane & 15;

  const int r0 = tid >> 2;
  const int c8 = (tid & 3) * 8;
  const unsigned short* Ag0 = A + (size_t)(row0 + r0) * K + c8;
  const unsigned short* Ag1 = A + (size_t)(row0 + r0 + 64) * K + c8;
  const unsigned short* Bg0 = Bt + (size_t)(col0 + r0) * K + c8;
  const unsigned short* Bg1 = Bt + (size_t)(col0 + r0 + 64) * K + c8;
  char* AsB = (char*)As;
  char* BsB = (char*)Bs;
  const int wb = wave * 1024;

  f32x4 acc[4][4] = {};
  for (int k0 = 0; k0 < K; k0 += 32) {
    gload_lds16(Ag0 + k0, AsB + wb);
    gload_lds16(Ag1 + k0, AsB + 4096 + wb);
    gload_lds16(Bg0 + k0, BsB + wb);
    gload_lds16(Bg1 + k0, BsB + 4096 + wb);
    __syncthreads();
    short8 af[4], bf[4];
#pragma unroll
    for (int i = 0; i < 4; i++) {
      af[i] = *(const short8*)&As[(wm + i * 16 + m16) * 32 + quad * 8];
      bf[i] = *(const short8*)&Bs[(wn + i * 16 + m16) * 32 + quad * 8];
    }
#pragma unroll
    for (int i = 0; i < 4; i++)
#pragma unroll
      for (int j = 0; j < 4; j++)
        acc[i][j] = __builtin_amdgcn_mfma_f32_16x16x32_bf16(af[i], bf[j], acc[i][j], 0, 0, 0);
    __syncthreads();
  }
#pragma unroll
  for (int i = 0; i < 4; i++) {
#pragma unroll
    for (int r = 0; r < 4; r++) {
      int gr = row0 + wm + i * 16 + quad * 4 + r;
      if (gr < Mstore) {
#pragma unroll
        for (int j = 0; j < 4; j++) {
          int gc = col0 + wn + j * 16 + m16;
          float v = acc[i][j][r];
          if (EPI == 1) { v += bias[gc]; v = fmaxf(v, 0.f); }
          if (EPI == 2) { v += bias[gc] + C[(size_t)gr * N + gc]; }
          C[(size_t)gr * N + gc] = v;
        }
      }
    }
  }
}

// ---------------------------------------------------------------------------
// bf16 MFMA batched (8 heads) 256x256x256 GEMM for pinv.
// ---------------------------------------------------------------------------
template<bool WN, bool WT>
__global__ __launch_bounds__(256) void bmm_pinv(
    const unsigned short* __restrict__ A, const unsigned short* __restrict__ Bt,
    unsigned short* __restrict__ Cn, unsigned short* __restrict__ Ct,
    float an, float bn, float at, float bt)
{
  const int hh = blockIdx.z;
  A  += (size_t)hh << 16;
  Bt += (size_t)hh << 16;
  __shared__ unsigned short As[128 * 32];
  __shared__ unsigned short Bs[128 * 32];
  const int tid = threadIdx.x;
  const int row0 = blockIdx.y * 128, col0 = blockIdx.x * 128;
  const int wave = tid >> 6, lane = tid & 63;
  const int wm = (wave >> 1) * 64, wn = (wave & 1) * 64;
  const int quad = lane >> 4, m16 = lane & 15;
  const int r0 = tid >> 2, c8 = (tid & 3) * 8;
  const unsigned short* Ag0 = A + (size_t)(row0 + r0) * 256 + c8;
  const unsigned short* Ag1 = A + (size_t)(row0 + r0 + 64) * 256 + c8;
  const unsigned short* Bg0 = Bt + (size_t)(col0 + r0) * 256 + c8;
  const unsigned short* Bg1 = Bt + (size_t)(col0 + r0 + 64) * 256 + c8;
  char* AsB = (char*)As; char* BsB = (char*)Bs;
  const int wb = wave * 1024;
  f32x4 acc[4][4] = {};
  for (int k0 = 0; k0 < 256; k0 += 32) {
    gload_lds16(Ag0 + k0, AsB + wb);
    gload_lds16(Ag1 + k0, AsB + 4096 + wb);
    gload_lds16(Bg0 + k0, BsB + wb);
    gload_lds16(Bg1 + k0, BsB + 4096 + wb);
    __syncthreads();
    short8 af[4], bf[4];
#pragma unroll
    for (int i = 0; i < 4; i++) {
      af[i] = *(const short8*)&As[(wm + i * 16 + m16) * 32 + quad * 8];
      bf[i] = *(const short8*)&Bs[(wn + i * 16 + m16) * 32 + quad * 8];
    }
#pragma unroll
    for (int i = 0; i < 4; i++)
#pragma unroll
      for (int j = 0; j < 4; j++)
        acc[i][j] = __builtin_amdgcn_mfma_f32_16x16x32_bf16(af[i], bf[j], acc[i][j], 0, 0, 0);
    __syncthreads();
  }
  unsigned short* CnH = Cn + ((size_t)hh << 16);
  unsigned short* CtH = Ct + ((size_t)hh << 16);
#pragma unroll
  for (int i = 0; i < 4; i++) {
#pragma unroll
    for (int r = 0; r < 4; r++) {
      int gr = row0 + wm + i * 16 + quad * 4 + r;
#pragma unroll
      for (int j = 0; j < 4; j++) {
        int gc = col0 + wn + j * 16 + m16;
        float p = acc[i][j][r];
        float diag = (gr == gc) ? 1.f : 0.f;
        if (WN) CnH[(size_t)gr * 256 + gc] = f2bf(an * p + bn * diag);
        if (WT) CtH[(size_t)gc * 256 + gr] = f2bf(at * p + bt * diag);
      }
    }
  }
}

// cast fp32 -> bf16, pad (zero) past nvalid elements
__global__ void castpad_x(const float* __restrict__ x, unsigned short* __restrict__ xb,
                          size_t nvalid) {
  size_t i4 = ((size_t)blockIdx.x * 256 + threadIdx.x) * 4;
  float4 v = make_float4(0.f, 0.f, 0.f, 0.f);
  if (i4 < nvalid) v = *(const float4*)(x + i4);
  ushort4 o;
  o.x = f2bf(v.x); o.y = f2bf(v.y); o.z = f2bf(v.z); o.w = f2bf(v.w);
  *(ushort4*)(xb + i4) = o;
}

// in fp32 [R][C] -> out bf16 [C][R]
__global__ __launch_bounds__(256) void transpose_cast(
    const float* __restrict__ in, unsigned short* __restrict__ out, int R, int C)
{
  __shared__ float tile[32][33];
  int r0 = blockIdx.x * 32, c0 = blockIdx.y * 32;
  int tx = threadIdx.x & 31, ty = threadIdx.x >> 5;
  for (int yy = ty; yy < 32; yy += 8)
    tile[yy][tx] = in[(size_t)(r0 + yy) * C + c0 + tx];
  __syncthreads();
  for (int yy = ty; yy < 32; yy += 8)
    out[(size_t)(c0 + yy) * R + r0 + tx] = f2bf(tile[tx][yy]);
}

// ---------------------------------------------------------------------------
// one-pass qkv postprocess: qb=bf16(q*0.125) [n][512], kb=bf16(k) [n][512],
// pooled q_l/k_l (f32 + bf16). grid 256 (landmark groups), block 1024.
// ---------------------------------------------------------------------------
__global__ __launch_bounds__(1024) void qkv_prep(
    const float* __restrict__ qkv,
    unsigned short* __restrict__ qb, unsigned short* __restrict__ kb,
    float* __restrict__ q_l, float* __restrict__ k_l,
    unsigned short* __restrict__ q_lb, unsigned short* __restrict__ k_lb)
{
  const int j = blockIdx.x, t = threadIdx.x;
  const int cs = t & 255, rg = t >> 8;        // col-slot, row-group
  const int c = cs * 4;                       // 0..1023: q cols then k cols
  const bool isq = c < 512;
  __shared__ float4 pbuf[4][256];
  float4 acc = make_float4(0.f, 0.f, 0.f, 0.f);
  for (int r = rg * 16; r < rg * 16 + 16; r++) {
    int row = j * 64 + r;
    float4 v = *(const float4*)(qkv + (size_t)row * 1536 + c);
    acc.x += v.x; acc.y += v.y; acc.z += v.z; acc.w += v.w;
    ushort4 o;
    if (isq) {
      o.x = f2bf(v.x * 0.125f); o.y = f2bf(v.y * 0.125f);
      o.z = f2bf(v.z * 0.125f); o.w = f2bf(v.w * 0.125f);
      *(ushort4*)(qb + (size_t)row * 512 + c) = o;
    } else {
      o.x = f2bf(v.x); o.y = f2bf(v.y); o.z = f2bf(v.z); o.w = f2bf(v.w);
      *(ushort4*)(kb + (size_t)row * 512 + (c - 512)) = o;
    }
  }
  pbuf[rg][cs] = acc;
  __syncthreads();
  if (rg == 0) {
    float4 a0 = pbuf[0][cs], a1 = pbuf[1][cs], a2 = pbuf[2][cs], a3 = pbuf[3][cs];
    float sc = (1.f / 64.f) * (isq ? 0.125f : 1.f);
    float4 p;
    p.x = (a0.x + a1.x + a2.x + a3.x) * sc;
    p.y = (a0.y + a1.y + a2.y + a3.y) * sc;
    p.z = (a0.z + a1.z + a2.z + a3.z) * sc;
    p.w = (a0.w + a1.w + a2.w + a3.w) * sc;
    int cc = isq ? c : c - 512;
    int hh = cc >> 6, d = cc & 63;
    size_t o = ((size_t)(hh * 256 + j)) * 64 + d;
    ushort4 ob;
    ob.x = f2bf(p.x); ob.y = f2bf(p.y); ob.z = f2bf(p.z); ob.w = f2bf(p.w);
    if (isq) { *(float4*)(q_l + o) = p; *(ushort4*)(q_lb + o) = ob; }
    else     { *(float4*)(k_l + o) = p; *(ushort4*)(k_lb + o) = ob; }
  }
}

// vTb[c][i] = bf16(qkv[i][1024 + c])   [512][16384]
__global__ __launch_bounds__(256) void transpose_cast_v(
    const float* __restrict__ qkv, unsigned short* __restrict__ vTb)
{
  __shared__ float tile[32][33];
  int i0 = blockIdx.x * 32, c0 = blockIdx.y * 32;
  int tx = threadIdx.x & 31, ty = threadIdx.x >> 5;
  for (int yy = ty; yy < 32; yy += 8)
    tile[yy][tx] = qkv[(size_t)(i0 + yy) * 1536 + 1024 + c0 + tx];
  __syncthreads();
  for (int yy = ty; yy < 32; yy += 8)
    vTb[(size_t)(c0 + yy) * NTOK + i0 + tx] = f2bf(tile[tx][yy]);
}

// depthwise conv over sequence: convT[c][i] = sum_u rk[c>>6][u] * vT[c][i+u-16]
// grid (8 i-chunks, 512 c), block 256, 8 outputs/thread
__global__ __launch_bounds__(256) void conv_seq(
    const unsigned short* __restrict__ vTb, const float* __restrict__ res_k,
    unsigned short* __restrict__ convT)
{
  const int c = blockIdx.y;
  const int h = c >> 6;
  const int i0 = (blockIdx.x * 256 + threadIdx.x) * 8;
  float rk[33];
#pragma unroll
  for (int u = 0; u < 33; u++) rk[u] = res_k[h * 33 + u];
  const unsigned short* vr = vTb + (size_t)c * NTOK;
  float win[40];
#pragma unroll
  for (int ch = 0; ch < 5; ch++) {
    int a = i0 - 16 + ch * 8;
    if (a >= 0 && a < NTOK) {
      ushort4 u0 = *(const ushort4*)(vr + a);
      ushort4 u1 = *(const ushort4*)(vr + a + 4);
      win[ch * 8 + 0] = bf2f(u0.x); win[ch * 8 + 1] = bf2f(u0.y);
      win[ch * 8 + 2] = bf2f(u0.z); win[ch * 8 + 3] = bf2f(u0.w);
      win[ch * 8 + 4] = bf2f(u1.x); win[ch * 8 + 5] = bf2f(u1.y);
      win[ch * 8 + 6] = bf2f(u1.z); win[ch * 8 + 7] = bf2f(u1.w);
    } else {
#pragma unroll
      for (int u = 0; u < 8; u++) win[ch * 8 + u] = 0.f;
    }
  }
  ushort4 o0, o1;
  float out[8];
#pragma unroll
  for (int jj = 0; jj < 8; jj++) {
    float s = 0.f;
#pragma unroll
    for (int u = 0; u < 33; u++) s += rk[u] * win[jj + u];
    out[jj] = s;
  }
  o0.x = f2bf(out[0]); o0.y = f2bf(out[1]); o0.z = f2bf(out[2]); o0.w = f2bf(out[3]);
  o1.x = f2bf(out[4]); o1.y = f2bf(out[5]); o1.z = f2bf(out[6]); o1.w = f2bf(out[7]);
  *(ushort4*)(convT + (size_t)c * NTOK + i0) = o0;
  *(ushort4*)(convT + (size_t)c * NTOK + i0 + 4) = o1;
}

__global__ void cast_bf2f(const unsigned short* __restrict__ in, float* __restrict__ out) {
  int i = blockIdx.x * 256 + threadIdx.x;
  out[i] = bf2f(in[i]);
}

// ---------------------------------------------------------------------------
// fp32 batched GEMM (pinv polish): C = alpha*(A@B) + beta*I ; opt C2 = gamma*I - C
// ---------------------------------------------------------------------------
template<bool W2>
__global__ __launch_bounds__(256) void bmm_f32(
    const float* __restrict__ A, const float* __restrict__ B, float* __restrict__ C,
    float* __restrict__ C2, int M, int N, int K, float alpha, float beta, float gamma)
{
  const int h = blockIdx.z;
  A += (size_t)h * M * K; B += (size_t)h * K * N;
  size_t cb = (size_t)h * M * N;
  __shared__ float As[16][64];
  __shared__ float Bs[16][64];
  const int tid = threadIdx.x;
  const int row0 = blockIdx.y * 64, col0 = blockIdx.x * 64;
  const int ty = tid >> 4, tx = tid & 15;
  const int ar = tid >> 2, ac = (tid & 3) << 2;
  const int bk = tid >> 4, bj = (tid & 15) << 2;
  float acc[4][4] = {};
  for (int k0 = 0; k0 < K; k0 += 16) {
    float4 a = *(const float4*)(A + (size_t)(row0 + ar) * K + k0 + ac);
    As[ac + 0][ar] = a.x; As[ac + 1][ar] = a.y; As[ac + 2][ar] = a.z; As[ac + 3][ar] = a.w;
    *(float4*)&Bs[bk][bj] = *(const float4*)(B + (size_t)(k0 + bk) * N + col0 + bj);
    __syncthreads();
#pragma unroll
    for (int kk = 0; kk < 16; kk++) {
      float4 av = *(float4*)&As[kk][ty << 2];
      float4 bv = *(float4*)&Bs[kk][tx << 2];
      float a4[4] = {av.x, av.y, av.z, av.w};
      float b4[4] = {bv.x, bv.y, bv.z, bv.w};
#pragma unroll
      for (int ii = 0; ii < 4; ii++)
#pragma unroll
        for (int jj = 0; jj < 4; jj++) acc[ii][jj] += a4[ii] * b4[jj];
    }
    __syncthreads();
  }
#pragma unroll
  for (int ii = 0; ii < 4; ii++) {
    int gr = row0 + (ty << 2) + ii;
#pragma unroll
    for (int jj = 0; jj < 4; jj++) {
      int gc = col0 + (tx << 2) + jj;
      float diag = (gr == gc) ? 1.f : 0.f;
      float v = alpha * acc[ii][jj] + beta * diag;
      C[cb + (size_t)gr * N + gc] = v;
      if (W2) C2[cb + (size_t)gr * N + gc] = gamma * diag - v;
    }
  }
}

__global__ void cls_copy(const float* __restrict__ cls, float* __restrict__ h) {
  int t = threadIdx.x;
  if (t < 512) h[t] = cls[t];
}

// per-row layernorm over 512, writes bf16
__global__ __launch_bounds__(256) void layernorm_rows(
    const float* __restrict__ x, unsigned short* __restrict__ y,
    const float* __restrict__ w, const float* __restrict__ b)
{
  const int row = blockIdx.x, tid = threadIdx.x;
  const float* xr = x + (size_t)row * NDIM;
  float2 v = ((const float2*)xr)[tid];
  float sum = v.x + v.y, sq = v.x * v.x + v.y * v.y;
#pragma unroll
  for (int off = 32; off; off >>= 1) { sum += __shfl_xor(sum, off); sq += __shfl_xor(sq, off); }
  __shared__ float r1[4], r2[4];
  if ((tid & 63) == 0) { r1[tid >> 6] = sum; r2[tid >> 6] = sq; }
  __syncthreads();
  sum = r1[0] + r1[1] + r1[2] + r1[3];
  sq  = r2[0] + r2[1] + r2[2] + r2[3];
  float mu = sum * (1.f / 512.f);
  float var = sq * (1.f / 512.f) - mu * mu;
  float rs = rsqrtf(var + 1e-5f);
  float a = (v.x - mu) * rs * w[2 * tid]     + b[2 * tid];
  float c = (v.y - mu) * rs * w[2 * tid + 1] + b[2 * tid + 1];
  ((unsigned*)(y + (size_t)row * NDIM))[tid] = (unsigned)f2bf(a) | ((unsigned)f2bf(c) << 16);
}

// attn2 = softmax(q_l @ k_l^T) rows; fp32 + bf16 outputs
__global__ __launch_bounds__(256) void attn2_softmax(
    const float* __restrict__ q_l, const float* __restrict__ k_l,
    float* __restrict__ x2, unsigned short* __restrict__ x2b)
{
  int row = blockIdx.x, h = blockIdx.y, j = threadIdx.x;
  __shared__ float qrow[64];
  __shared__ float red[4];
  if (j < 64) qrow[j] = q_l[(size_t)(h * 256 + row) * 64 + j];
  __syncthreads();
  const float* kr = k_l + (size_t)(h * 256 + j) * 64;
  float s = 0.f;
#pragma unroll 8
  for (int d = 0; d < 64; d++) s += qrow[d] * kr[d];
  float m = s;
#pragma unroll
  for (int off = 32; off; off >>= 1) m = fmaxf(m, __shfl_xor(m, off));
  if ((j & 63) == 0) red[j >> 6] = m;
  __syncthreads();
  m = fmaxf(fmaxf(red[0], red[1]), fmaxf(red[2], red[3]));
  __syncthreads();
  float e = __expf(s - m), l = e;
#pragma unroll
  for (int off = 32; off; off >>= 1) l += __shfl_xor(l, off);
  if ((j & 63) == 0) red[j >> 6] = l;
  __syncthreads();
  l = red[0] + red[1] + red[2] + red[3];
  float val = e / l;
  size_t o = ((size_t)(h * 256 + row) << 8) + j;
  x2[o] = val;
  x2b[o] = f2bf(val);
}

__global__ __launch_bounds__(256) void colrow_max(const float* __restrict__ x2,
                                                  float* __restrict__ scal)
{
  int t = threadIdx.x, r = blockIdx.x, h = blockIdx.y;
  float rv = x2[((size_t)(h * 256 + r) << 8) + t];
  float cv = x2[((size_t)(h * 256 + t) << 8) + r];
#pragma unroll
  for (int off = 32; off; off >>= 1) { rv += __shfl_xor(rv, off); cv += __shfl_xor(cv, off); }
  __shared__ float rr[4], cc[4];
  if ((t & 63) == 0) { rr[t >> 6] = rv; cc[t >> 6] = cv; }
  __syncthreads();
  if (t == 0) {
    float rs = rr[0] + rr[1] + rr[2] + rr[3];
    float cs = cc[0] + cc[1] + cc[2] + cc[3];
    atomicMax((unsigned int*)&scal[0], __float_as_uint(rs));
    atomicMax((unsigned int*)&scal[1], __float_as_uint(cs));
  }
}

// z0 (bf16, [j][i]) and z0^T (bf16, [i][j]) from x2
__global__ void zinit_bf(const float* __restrict__ x2, unsigned short* __restrict__ zb,
                         unsigned short* __restrict__ zTb, const float* __restrict__ scal)
{
  int idx = blockIdx.x * 256 + threadIdx.x;
  int hh = idx >> 16, i = (idx >> 8) & 255, j = idx & 255;
  float den = scal[0] * scal[1];
  float val = x2[idx] / den;
  unsigned short b = f2bf(val);
  zTb[idx] = b;
  zb[(hh << 16) + (j << 8) + i] = b;
}

// ---------------------------------------------------------------------------
// single-pass MFMA flash attn3@v with key-split partials.
// ---------------------------------------------------------------------------
__global__ __launch_bounds__(256) void flash_fused(
    const unsigned short* __restrict__ q_lb, const unsigned short* __restrict__ kb,
    const unsigned short* __restrict__ vTb,
    float* __restrict__ Opart, float* __restrict__ mlpart)
{
  const int ks = blockIdx.x, qg = blockIdx.y, h = blockIdx.z;
  const int tid = threadIdx.x;
  const int wave = tid >> 6, lane = tid & 63;
  const int quad = lane >> 4, m16 = lane & 15;
  __shared__ unsigned short pbuf_all[4][16 * 72];
  unsigned short* pbuf = pbuf_all[wave];

  const int qrow_w = qg * 64 + wave * 16;
  const unsigned short* qbase = q_lb + ((size_t)h << 14) + (size_t)(qrow_w + m16) * 64;
  short8 aq0 = *(const short8*)(qbase + quad * 8);
  short8 aq1 = *(const short8*)(qbase + 32 + quad * 8);

  float m_e[4], l_e[4];
#pragma unroll
  for (int e = 0; e < 4; e++) { m_e[e] = -1e30f; l_e[e] = 0.f; }
  f32x4 acc_o[4] = {};

  const int key00 = ks * 512;
  for (int c = 0; c < 8; c++) {
    const int key0 = key00 + c * 64;
    f32x4 s[4] = {};
#pragma unroll
    for (int kt = 0; kt < 4; kt++) {
      const unsigned short* kr = kb + (size_t)(key0 + kt * 16 + m16) * 512 + (h << 6);
      short8 b0 = *(const short8*)(kr + quad * 8);
      short8 b1 = *(const short8*)(kr + 32 + quad * 8);
      s[kt] = __builtin_amdgcn_mfma_f32_16x16x32_bf16(aq0, b0, s[kt], 0, 0, 0);
      s[kt] = __builtin_amdgcn_mfma_f32_16x16x32_bf16(aq1, b1, s[kt], 0, 0, 0);
    }
#pragma unroll
    for (int e = 0; e < 4; e++) {
      float mx = fmaxf(fmaxf(s[0][e], s[1][e]), fmaxf(s[2][e], s[3][e]));
      mx = fmaxf(mx, __shfl_xor(mx, 1));
      mx = fmaxf(mx, __shfl_xor(mx, 2));
      mx = fmaxf(mx, __shfl_xor(mx, 4));
      mx = fmaxf(mx, __shfl_xor(mx, 8));
      float mn = fmaxf(m_e[e], mx);
      float scale = __expf(m_e[e] - mn);
      m_e[e] = mn;
      float sum = 0.f;
#pragma unroll
      for (int kt = 0; kt < 4; kt++) {
        float ev = __expf(s[kt][e] - mn);
        s[kt][e] = ev;
        sum += ev;
      }
      sum += __shfl_xor(sum, 1); sum += __shfl_xor(sum, 2);
      sum += __shfl_xor(sum, 4); sum += __shfl_xor(sum, 8);
      l_e[e] = l_e[e] * scale + sum;
#pragma unroll
      for (int dt = 0; dt < 4; dt++) acc_o[dt][e] *= scale;
    }
#pragma unroll
    for (int kt = 0; kt < 4; kt++)
#pragma unroll
      for (int e = 0; e < 4; e++)
        pbuf[(quad * 4 + e) * 72 + kt * 16 + m16] = f2bf(s[kt][e]);
    asm volatile("s_waitcnt lgkmcnt(0)" ::: "memory");
    short8 ap0 = *(const short8*)&pbuf[m16 * 72 + quad * 8];
    short8 ap1 = *(const short8*)&pbuf[m16 * 72 + 32 + quad * 8];
#pragma unroll
    for (int dt = 0; dt < 4; dt++) {
      const unsigned short* vr = vTb + (size_t)((h << 6) + dt * 16 + m16) * NTOK + key0;
      short8 bv0 = *(const short8*)(vr + quad * 8);
      short8 bv1 = *(const short8*)(vr + 32 + quad * 8);
      acc_o[dt] = __builtin_amdgcn_mfma_f32_16x16x32_bf16(ap0, bv0, acc_o[dt], 0, 0, 0);
      acc_o[dt] = __builtin_amdgcn_mfma_f32_16x16x32_bf16(ap1, bv1, acc_o[dt], 0, 0, 0);
    }
  }
  float* ob = Opart + ((size_t)(ks * 8 + h) * 256 + qrow_w) * 64;
#pragma unroll
  for (int dt = 0; dt < 4; dt++)
#pragma unroll
    for (int e = 0; e < 4; e++)
      ob[(size_t)(quad * 4 + e) * 64 + dt * 16 + m16] = acc_o[dt][e];
  if (m16 == 0) {
    float* mlb = mlpart + ((size_t)(ks * 8 + h) * 256 + qrow_w) * 2;
#pragma unroll
    for (int e = 0; e < 4; e++) {
      mlb[(quad * 4 + e) * 2]     = m_e[e];
      mlb[(quad * 4 + e) * 2 + 1] = l_e[e];
    }
  }
}

// combine key-split partials -> kv[h][256][64]
__global__ __launch_bounds__(256) void flash_merge(
    const float* __restrict__ Opart, const float* __restrict__ mlpart,
    float* __restrict__ kv)
{
  const int rc = blockIdx.x, h = blockIdx.y, tid = threadIdx.x;
  const int r = rc * 32 + (tid >> 3);
  const int d0 = (tid & 7) * 8;
  float M = -1e30f;
  for (int ks = 0; ks < 32; ks++)
    M = fmaxf(M, mlpart[((size_t)(ks * 8 + h) * 256 + r) * 2]);
  float L = 0.f;
  float o[8];
#pragma unroll
  for (int j = 0; j < 8; j++) o[j] = 0.f;
  for (int ks = 0; ks < 32; ks++) {
    const float* mlb = mlpart + ((size_t)(ks * 8 + h) * 256 + r) * 2;
    float w = __expf(mlb[0] - M);
    L += mlb[1] * w;
    const float* op = Opart + ((size_t)(ks * 8 + h) * 256 + r) * 64 + d0;
    float4 a = *(const float4*)op;
    float4 b = *(const float4*)(op + 4);
    o[0] += a.x * w; o[1] += a.y * w; o[2] += a.z * w; o[3] += a.w * w;
    o[4] += b.x * w; o[5] += b.y * w; o[6] += b.z * w; o[7] += b.w * w;
  }
  float invL = 1.f / L;
  float* out = kv + ((size_t)(h * 256 + r)) * 64 + d0;
#pragma unroll
  for (int j = 0; j < 8; j++) out[j] = o[j] * invL;
}

// BmT[h][d][j] = sum_k zf[h][j][k] * kv[h][k][d]  (bf16 out)
__global__ __launch_bounds__(256) void bmt_kernel(
    const float* __restrict__ zf, const float* __restrict__ kv,
    unsigned short* __restrict__ BmT)
{
  const int jb = blockIdx.x, hh = blockIdx.y, tid = threadIdx.x;
  __shared__ float zt[64 * 256];
  const float* zsrc = zf + ((size_t)hh << 16) + (size_t)(jb * 64) * 256;
  for (int rep = 0; rep < 16; rep++) {
    int e4 = (rep * 256 + tid) * 4;
    *(float4*)&zt[e4] = *(const float4*)(zsrc + e4);
  }
  __syncthreads();
  const int d = tid & 63, jg = tid >> 6;
  const float* kvh = kv + ((size_t)hh << 14) + d;
  float acc[16];
#pragma unroll
  for (int u = 0; u < 16; u++) acc[u] = 0.f;
  for (int k0 = 0; k0 < 256; k0 += 8) {
    float kv8[8];
#pragma unroll
    for (int u = 0; u < 8; u++) kv8[u] = kvh[(size_t)(k0 + u) << 6];
#pragma unroll
    for (int jj = 0; jj < 16; jj++) {
      const float* zr = &zt[(jg * 16 + jj) * 256 + k0];
#pragma unroll
      for (int u = 0; u < 8; u++) acc[jj] += zr[u] * kv8[u];
    }
  }
  unsigned short* ob = BmT + ((size_t)hh << 14) + (size_t)d * 256 + jb * 64 + jg * 16;
#pragma unroll
  for (int jj = 0; jj < 16; jj++) ob[jj] = f2bf(acc[jj]);
}

// ---------------------------------------------------------------------------
// fused attn1: softmax(q@k_l^T) @ Bm + precomputed conv -> attn_out bf16
// ---------------------------------------------------------------------------
__global__ __launch_bounds__(256) void attn1_out(
    const unsigned short* __restrict__ qb, const unsigned short* __restrict__ k_lb,
    const unsigned short* __restrict__ BmT, const unsigned short* __restrict__ convT,
    unsigned short* __restrict__ attn_out)
{
  const int qc = blockIdx.x, h = blockIdx.y, tid = threadIdx.x;
  const int q0 = qc * 32;
  const int wave = tid >> 6, lane = tid & 63;
  const int quad = lane >> 4, m16 = lane & 15;

  __shared__ unsigned short stp[32 * STP_LD];
  __shared__ float redm[4][32], redl[4][32];

  f32x4 acc1[2][4] = {};
  {
    const unsigned short* qbase = qb + (size_t)q0 * 512 + (h << 6);
    const unsigned short* kbase = k_lb + ((size_t)h << 14) + (size_t)(wave * 64) * 64;
#pragma unroll
    for (int kc = 0; kc < 2; kc++) {
      short8 aq[2], bk[4];
#pragma unroll
      for (int i = 0; i < 2; i++)
        aq[i] = *(const short8*)(qbase + (size_t)(i * 16 + m16) * 512 + kc * 32 + quad * 8);
#pragma unroll
      for (int n = 0; n < 4; n++)
        bk[n] = *(const short8*)(kbase + (size_t)(n * 16 + m16) * 64 + kc * 32 + quad * 8);
#pragma unroll
      for (int i = 0; i < 2; i++)
#pragma unroll
        for (int n = 0; n < 4; n++)
          acc1[i][n] = __builtin_amdgcn_mfma_f32_16x16x32_bf16(aq[i], bk[n], acc1[i][n], 0, 0, 0);
    }
  }
#pragma unroll
  for (int i = 0; i < 2; i++) {
#pragma unroll
    for (int e = 0; e < 4; e++) {
      float mx = fmaxf(fmaxf(acc1[i][0][e], acc1[i][1][e]), fmaxf(acc1[i][2][e], acc1[i][3][e]));
      mx = fmaxf(mx, __shfl_xor(mx, 1));
      mx = fmaxf(mx, __shfl_xor(mx, 2));
      mx = fmaxf(mx, __shfl_xor(mx, 4));
      mx = fmaxf(mx, __shfl_xor(mx, 8));
      if (m16 == 0) redm[wave][i * 16 + quad * 4 + e] = mx;
    }
  }
  __syncthreads();
#pragma unroll
  for (int i = 0; i < 2; i++) {
#pragma unroll
    for (int e = 0; e < 4; e++) {
      int r = i * 16 + quad * 4 + e;
      float gm = fmaxf(fmaxf(redm[0][r], redm[1][r]), fmaxf(redm[2][r], redm[3][r]));
      float s = 0.f;
#pragma unroll
      for (int n = 0; n < 4; n++) {
        float ev = __expf(acc1[i][n][e] - gm);
        acc1[i][n][e] = ev;
        s += ev;
      }
      s += __shfl_xor(s, 1); s += __shfl_xor(s, 2);
      s += __shfl_xor(s, 4); s += __shfl_xor(s, 8);
      if (m16 == 0) redl[wave][r] = s;
    }
  }
#pragma unroll
  for (int i = 0; i < 2; i++)
#pragma unroll
    for (int n = 0; n < 4; n++) {
      int col = wave * 64 + n * 16 + m16;
#pragma unroll
      for (int e = 0; e < 4; e++)
        stp[(i * 16 + quad * 4 + e) * STP_LD + col] = f2bf(acc1[i][n][e]);
    }
  __syncthreads();

  const int mi3 = (wave & 1) * 16;
  const int nbase = (wave >> 1) * 32;
  f32x4 acc3[2] = {};
  {
    const unsigned short* bbase = BmT + ((size_t)h << 14);
#pragma unroll
    for (int kc = 0; kc < 8; kc++) {
      short8 ap = *(const short8*)&stp[(mi3 + m16) * STP_LD + kc * 32 + quad * 8];
#pragma unroll
      for (int t = 0; t < 2; t++) {
        short8 bp = *(const short8*)(bbase + (size_t)(nbase + t * 16 + m16) * 256 + kc * 32 + quad * 8);
        acc3[t] = __builtin_amdgcn_mfma_f32_16x16x32_bf16(ap, bp, acc3[t], 0, 0, 0);
      }
    }
  }
  const int gi0 = q0 + mi3 + quad * 4;
#pragma unroll
  for (int t = 0; t < 2; t++) {
    int d = nbase + t * 16 + m16;
    ushort4 cv4 = *(const ushort4*)(convT + (size_t)((h << 6) + d) * NTOK + gi0);
    unsigned short cvs[4] = {cv4.x, cv4.y, cv4.z, cv4.w};
#pragma unroll
    for (int e = 0; e < 4; e++) {
      int lr = mi3 + quad * 4 + e;
      float l = redl[0][lr] + redl[1][lr] + redl[2][lr] + redl[3][lr];
      float v = acc3[t][e] / l + bf2f(cvs[e]);
      attn_out[((size_t)(gi0 + e) << 9) + (h << 6) + d] = f2bf(v);
    }
  }
}

// final: layernorm row0 -> 4 logits -> sigmoid + cumprod
__global__ __launch_bounds__(256) void final_head(
    const float* __restrict__ hrow, const float* __restrict__ nw, const float* __restrict__ nb,
    const float* __restrict__ cw, const float* __restrict__ cb, float* __restrict__ out)
{
  const int tid = threadIdx.x;
  __shared__ float ln0[512];
  __shared__ float r1[4], r2[4];
  __shared__ float lg[4][4];
  float2 v = ((const float2*)hrow)[tid];
  float sum = v.x + v.y, sq = v.x * v.x + v.y * v.y;
#pragma unroll
  for (int off = 32; off; off >>= 1) { sum += __shfl_xor(sum, off); sq += __shfl_xor(sq, off); }
  if ((tid & 63) == 0) { r1[tid >> 6] = sum; r2[tid >> 6] = sq; }
  __syncthreads();
  sum = r1[0] + r1[1] + r1[2] + r1[3];
  sq  = r2[0] + r2[1] + r2[2] + r2[3];
  float mu = sum * (1.f / 512.f);
  float var = sq * (1.f / 512.f) - mu * mu;
  float rs = rsqrtf(var + 1e-5f);
  ln0[2 * tid]     = (v.x - mu) * rs * nw[2 * tid]     + nb[2 * tid];
  ln0[2 * tid + 1] = (v.y - mu) * rs * nw[2 * tid + 1] + nb[2 * tid + 1];
  __syncthreads();
  float p[4] = {0.f, 0.f, 0.f, 0.f};
  for (int k = tid; k < 512; k += 256) {
    float lv = ln0[k];
#pragma unroll
    for (int c = 0; c < 4; c++) p[c] += lv * cw[k * 4 + c];
  }
#pragma unroll
  for (int off = 32; off; off >>= 1)
#pragma unroll
    for (int c = 0; c < 4; c++) p[c] += __shfl_xor(p[c], off);
  if ((tid & 63) == 0) {
    int w = tid >> 6;
#pragma unroll
    for (int c = 0; c < 4; c++) lg[w][c] = p[c];
  }
  __syncthreads();
  if (tid == 0) {
    float cum = 1.f;
    for (int c = 0; c < 4; c++) {
      float logit = lg[0][c] + lg[1][c] + lg[2][c] + lg[3][c] + cb[c];
      float hz = 1.f / (1.f + __expf(-logit));
      out[c] = hz;
      cum *= (1.f - hz);
      out[4 + c] = cum;
    }
  }
}

// ---------------------------------------------------------------------------
extern "C" void kernel_launch(void* const* d_in, const int* in_sizes, int n_in,
                              void* d_out, int out_size, void* d_ws, size_t ws_size,
                              hipStream_t stream)
{
  (void)in_sizes; (void)n_in; (void)out_size; (void)ws_size;
  const float* x    = (const float*)d_in[0];
  const float* fc_w = (const float*)d_in[1];
  const float* fc_b = (const float*)d_in[2];
  const float* cls  = (const float*)d_in[3];
  const float* nw[2]   = {(const float*)d_in[4],  (const float*)d_in[10]};
  const float* nb[2]   = {(const float*)d_in[5],  (const float*)d_in[11]};
  const float* qkvw[2] = {(const float*)d_in[6],  (const float*)d_in[12]};
  const float* outw[2] = {(const float*)d_in[7],  (const float*)d_in[13]};
  const float* outb[2] = {(const float*)d_in[8],  (const float*)d_in[14]};
  const float* resk[2] = {(const float*)d_in[9],  (const float*)d_in[15]};
  const float* fnw = (const float*)d_in[16];
  const float* fnb = (const float*)d_in[17];
  const float* cw  = (const float*)d_in[18];
  const float* cb  = (const float*)d_in[19];

  float* ws = (float*)d_ws;
  float* h    = ws; ws += (size_t)NTOK * NDIM;
  float* qkv  = ws; ws += (size_t)NTOK * 1536;   // aliases: xb pre-loop; Opart/mlpart/convT after prep
  float* bigv = ws; ws += (size_t)(512 * NTOK) / 2;   // vTb (bf16) home
  float* q_l  = ws; ws += 8 * 256 * 64;
  float* k_l  = ws; ws += 8 * 256 * 64;
  float* x2   = ws; ws += 8 * 256 * 256;
  float* zf   = ws; ws += 8 * 256 * 256;
  float* zfin = ws; ws += 8 * 256 * 256;
  float* tA   = ws; ws += 8 * 256 * 256;
  float* tB   = ws; ws += 8 * 256 * 256;
  float* tC   = ws; ws += 8 * 256 * 256;
  float* kv   = ws; ws += 8 * 256 * 64;
  float* scal = ws; ws += 64;
  unsigned short* actb = (unsigned short*)ws; ws += (size_t)NTOK * NDIM / 2;  // also kb
  unsigned short* wT   = (unsigned short*)ws; ws += (1536 * 512) / 2;
  unsigned short* qb   = (unsigned short*)ws; ws += (size_t)NTOK * NDIM / 2;
  unsigned short* k_lb = (unsigned short*)ws; ws += (8 * 256 * 64) / 2;
  unsigned short* q_lb = (unsigned short*)ws; ws += (8 * 256 * 64) / 2;
  unsigned short* x2b  = (unsigned short*)ws; ws += (8 * 256 * 256) / 2;
  unsigned short* zb0  = (unsigned short*)ws; ws += (8 * 256 * 256) / 2;
  unsigned short* zb1  = (unsigned short*)ws; ws += (8 * 256 * 256) / 2;
  unsigned short* zT0  = (unsigned short*)ws; ws += (8 * 256 * 256) / 2;
  unsigned short* zT1  = (unsigned short*)ws; ws += (8 * 256 * 256) / 2;
  unsigned short* xzb  = (unsigned short*)ws; ws += (8 * 256 * 256) / 2;
  unsigned short* t1T  = (unsigned short*)ws; ws += (8 * 256 * 256) / 2;
  unsigned short* t2T  = (unsigned short*)ws; ws += (8 * 256 * 256) / 2;
  unsigned short* t3T  = (unsigned short*)ws; ws += (8 * 256 * 256) / 2;
  unsigned short* BmT  = (unsigned short*)ws; ws += (8 * 64 * 256) / 2;

  unsigned short* xb  = (unsigned short*)qkv;   // bf16 padded x, dead before qkv use
  unsigned short* kb  = actb;                   // ln-out dead after qkv gemm
  unsigned short* vTb = (unsigned short*)bigv;
  // qkv region is dead after qkv_prep + transpose_cast_v:
  float* Opart  = qkv;                                          // 32*8*256*64 f32
  float* mlpart = qkv + (size_t)32 * 8 * 256 * 64;              // 32*8*256*2 f32
  unsigned short* convT = (unsigned short*)(qkv + (size_t)32 * 8 * 256 * 64 + 32 * 8 * 256 * 2);

  unsigned short* zbp[2] = {zb0, zb1};
  unsigned short* zTp[2] = {zT0, zT1};

  // ---- fc + relu ----
  castpad_x<<<16384, 256, 0, stream>>>(x, xb, (size_t)16383 * 1024);
  transpose_cast<<<dim3(32, 16), 256, 0, stream>>>(fc_w, wT, 1024, 512);
  gemm_bf16<1><<<dim3(4, 128), 256, 0, stream>>>(xb, wT, h + 512, fc_b,
                                                 16384, 512, 1024, 16383);
  cls_copy<<<1, 512, 0, stream>>>(cls, h);

  for (int L = 0; L < 2; L++) {
    layernorm_rows<<<NTOK, 256, 0, stream>>>(h, actb, nw[L], nb[L]);
    transpose_cast<<<dim3(16, 48), 256, 0, stream>>>(qkvw[L], wT, 512, 1536);
    gemm_bf16<0><<<dim3(12, 128), 256, 0, stream>>>(actb, wT, qkv, nullptr,
                                                    NTOK, 1536, 512, NTOK);
    qkv_prep<<<256, 1024, 0, stream>>>(qkv, qb, kb, q_l, k_l, q_lb, k_lb);
    transpose_cast_v<<<dim3(512, 16), 256, 0, stream>>>(qkv, vTb);
    attn2_softmax<<<dim3(256, 8), 256, 0, stream>>>(q_l, k_l, x2, x2b);
    hipMemsetAsync(scal, 0, 2 * sizeof(float), stream);
    colrow_max<<<dim3(256, 8), 256, 0, stream>>>(x2, scal);
    zinit_bf<<<2048, 256, 0, stream>>>(x2, zbp[0], zTp[0], scal);

    // flash attn3@v (qkv region is now free -> Opart/mlpart)
    flash_fused<<<dim3(32, 4, 8), 256, 0, stream>>>(q_lb, kb, vTb, Opart, mlpart);
    flash_merge<<<dim3(8, 8), 256, 0, stream>>>(Opart, mlpart, kv);
    conv_seq<<<dim3(8, 512), 256, 0, stream>>>(vTb, resk[L], convT);

    // 5 bf16 Newton iterations + fp32 polish (eyesub folded into dual epilogue)
    int cur = 0;
    dim3 pg(2, 2, 8);
    for (int it = 0; it < 5; it++) {
      bmm_pinv<true,  true><<<pg, 256, 0, stream>>>(x2b, zTp[cur], xzb, t1T, 1.f, 0.f, -1.f, 7.f);
      bmm_pinv<false, true><<<pg, 256, 0, stream>>>(xzb, t1T, xzb, t2T, 0.f, 0.f, -1.f, 15.f);
      bmm_pinv<false, true><<<pg, 256, 0, stream>>>(xzb, t2T, xzb, t3T, 0.f, 0.f, -1.f, 13.f);
      bmm_pinv<true,  true><<<pg, 256, 0, stream>>>(zbp[cur], t3T, zbp[cur ^ 1], zTp[cur ^ 1],
                                                    0.25f, 0.f, 0.25f, 0.f);
      cur ^= 1;
    }
    cast_bf2f<<<2048, 256, 0, stream>>>(zbp[cur], zf);
    bmm_f32<true ><<<dim3(4, 4, 8), 256, 0, stream>>>(x2, zf, tA, tB, 256, 256, 256, 1.f, 0.f, 7.f);
    bmm_f32<false><<<dim3(4, 4, 8), 256, 0, stream>>>(tA, tB, tC, nullptr, 256, 256, 256, -1.f, 15.f, 0.f);
    bmm_f32<false><<<dim3(4, 4, 8), 256, 0, stream>>>(tA, tC, tB, nullptr, 256, 256, 256, -1.f, 13.f, 0.f);
    bmm_f32<false><<<dim3(4, 4, 8), 256, 0, stream>>>(zf, tB, zfin, nullptr, 256, 256, 256, 0.25f, 0.f, 0.f);

    bmt_kernel<<<dim3(4, 8), 256, 0, stream>>>(zfin, kv, BmT);
    attn1_out<<<dim3(512, 8), 256, 0, stream>>>(qb, k_lb, BmT, convT, actb);
    transpose_cast<<<dim3(16, 16), 256, 0, stream>>>(outw[L], wT, 512, 512);
    gemm_bf16<2><<<dim3(4, 128), 256, 0, stream>>>(actb, wT, h, outb[L],
                                                   NTOK, 512, 512, NTOK);
  }
  final_head<<<1, 256, 0, stream>>>(h, fnw, fnb, cw, cb, (float*)d_out);
}